// Round 2
// baseline (50605.801 us; speedup 1.0000x reference)
//
#include <hip/hip_runtime.h>
#include <math.h>

// GPT-2-ish forward: V=50257 E=1024 H=16 L=8 B=2 T=2048 HD=64 FF=4096
constexpr int Vv = 50257;
constexpr int Ee = 1024;
constexpr int Hh = 16;
constexpr int Ll = 8;
constexpr int Bb = 2;
constexpr int Tt = 2048;
constexpr int HDh = 64;
constexpr int FFf = 4096;
constexpr int BT = Bb * Tt;   // 4096 token rows

// ---------------------------------------------------------------- embedding
__global__ __launch_bounds__(256) void k_embed(const int* __restrict__ idx,
                                               const float* __restrict__ wte,
                                               const float* __restrict__ wpe,
                                               float* __restrict__ x) {
    const int row = blockIdx.x;           // 0..BT-1
    const int t = row % Tt;
    const int tok = idx[row];
    const int c = threadIdx.x * 4;        // 256 threads * 4 = 1024 = E
    const float4 a = *(const float4*)(wte + (size_t)tok * Ee + c);
    const float4 b = *(const float4*)(wpe + (size_t)t * Ee + c);
    *(float4*)(x + (size_t)row * Ee + c) =
        make_float4(a.x + b.x, a.y + b.y, a.z + b.z, a.w + b.w);
}

// ---------------------------------------------------------------- layernorm
__global__ __launch_bounds__(256) void k_ln(const float* __restrict__ x,
                                            const float* __restrict__ g,
                                            const float* __restrict__ b,
                                            float* __restrict__ out) {
    const int row = blockIdx.x;
    const int tid = threadIdx.x;
    const float* xr = x + (size_t)row * Ee;
    const float4 v = *(const float4*)(xr + tid * 4);
    float s  = v.x + v.y + v.z + v.w;
    float ss = v.x * v.x + v.y * v.y + v.z * v.z + v.w * v.w;
#pragma unroll
    for (int off = 32; off; off >>= 1) {
        s  += __shfl_down(s, off);
        ss += __shfl_down(ss, off);
    }
    __shared__ float red[8];
    const int wid = tid >> 6, lane = tid & 63;
    if (lane == 0) { red[wid] = s; red[4 + wid] = ss; }
    __syncthreads();
    const float S  = red[0] + red[1] + red[2] + red[3];
    const float SS = red[4] + red[5] + red[6] + red[7];
    const float mean = S * (1.f / Ee);
    const float var  = SS * (1.f / Ee) - mean * mean;
    const float inv  = rsqrtf(var + 1e-5f);
    const float4 gg = *(const float4*)(g + tid * 4);
    const float4 bb = *(const float4*)(b + tid * 4);
    float4 o;
    o.x = (v.x - mean) * inv * gg.x + bb.x;
    o.y = (v.y - mean) * inv * gg.y + bb.y;
    o.z = (v.z - mean) * inv * gg.z + bb.z;
    o.w = (v.w - mean) * inv * gg.w + bb.w;
    *(float4*)(out + (size_t)row * Ee + tid * 4) = o;
}

// ---------------------------------------------------------------- GEMM
__device__ __forceinline__ float gelu_exact(float v) {
    return 0.5f * v * (1.0f + erff(v * 0.70710678118654752f));
}

// C[M,N] = A[M,K] @ B + epilogue.
// BL=0: B is [K,N] row-major.  BL=1: B is [N,K] row-major (B transposed).
// EPI=0: none. EPI=2: +bias then GELU. EPI=3: +bias then +res (residual).
template <int BL, int EPI>
__global__ __launch_bounds__(256) void k_gemm(const float* __restrict__ A,
                                              const float* __restrict__ Bm,
                                              const float* __restrict__ bias,
                                              const float* __restrict__ res,
                                              float* __restrict__ C,
                                              int M, int N, int K) {
    __shared__ float As[16][128];
    __shared__ float Bs[16][128];
    const int tid = threadIdx.x;
    const int n0 = blockIdx.x * 128;
    const int m0 = blockIdx.y * 128;
    const int tx = tid & 15, ty = tid >> 4;

    float acc[8][8];
#pragma unroll
    for (int i = 0; i < 8; i++)
#pragma unroll
        for (int j = 0; j < 8; j++) acc[i][j] = 0.f;

    const int am = tid >> 2;          // 0..63
    const int ak = (tid & 3) * 4;     // 0,4,8,12

    for (int k0 = 0; k0 < K; k0 += 16) {
        // A tile: As[k][m] = A[m0+m][k0+k]   (M,K always multiples of 128/16)
#pragma unroll
        for (int p = 0; p < 2; p++) {
            const int mm = am + p * 64;
            const float4 a4 = *(const float4*)(A + (size_t)(m0 + mm) * K + k0 + ak);
            As[ak + 0][mm] = a4.x; As[ak + 1][mm] = a4.y;
            As[ak + 2][mm] = a4.z; As[ak + 3][mm] = a4.w;
        }
        if (BL == 0) {
#pragma unroll
            for (int p = 0; p < 2; p++) {
                const int kk = (tid >> 5) + p * 8;
                const int nn = (tid & 31) * 4;
                const int gn = n0 + nn;
                float4 b4;
                if (gn + 3 < N) {
                    b4 = *(const float4*)(Bm + (size_t)(k0 + kk) * N + gn);
                } else {
                    const float* bp = Bm + (size_t)(k0 + kk) * N;
                    b4.x = (gn + 0 < N) ? bp[gn + 0] : 0.f;
                    b4.y = (gn + 1 < N) ? bp[gn + 1] : 0.f;
                    b4.z = (gn + 2 < N) ? bp[gn + 2] : 0.f;
                    b4.w = (gn + 3 < N) ? bp[gn + 3] : 0.f;
                }
                *(float4*)&Bs[kk][nn] = b4;
            }
        } else {
#pragma unroll
            for (int p = 0; p < 2; p++) {
                const int nn = am + p * 64;
                const int gn = n0 + nn;
                float4 b4 = make_float4(0.f, 0.f, 0.f, 0.f);
                if (gn < N) b4 = *(const float4*)(Bm + (size_t)gn * K + k0 + ak);
                Bs[ak + 0][nn] = b4.x; Bs[ak + 1][nn] = b4.y;
                Bs[ak + 2][nn] = b4.z; Bs[ak + 3][nn] = b4.w;
            }
        }
        __syncthreads();
#pragma unroll
        for (int k = 0; k < 16; k++) {
            float a[8], b[8];
            *(float4*)&a[0] = *(const float4*)&As[k][ty * 8];
            *(float4*)&a[4] = *(const float4*)&As[k][ty * 8 + 4];
            *(float4*)&b[0] = *(const float4*)&Bs[k][tx * 8];
            *(float4*)&b[4] = *(const float4*)&Bs[k][tx * 8 + 4];
#pragma unroll
            for (int i = 0; i < 8; i++)
#pragma unroll
                for (int j = 0; j < 8; j++)
                    acc[i][j] = fmaf(a[i], b[j], acc[i][j]);
        }
        __syncthreads();
    }

#pragma unroll
    for (int i = 0; i < 8; i++) {
        const int gm = m0 + ty * 8 + i;
#pragma unroll
        for (int j4 = 0; j4 < 2; j4++) {
            const int gn = n0 + tx * 8 + j4 * 4;
            if (gn + 3 < N) {
                float4 v = make_float4(acc[i][j4 * 4 + 0], acc[i][j4 * 4 + 1],
                                       acc[i][j4 * 4 + 2], acc[i][j4 * 4 + 3]);
                if (EPI >= 2) {
                    v.x += bias[gn + 0]; v.y += bias[gn + 1];
                    v.z += bias[gn + 2]; v.w += bias[gn + 3];
                }
                if (EPI == 2) {
                    v.x = gelu_exact(v.x); v.y = gelu_exact(v.y);
                    v.z = gelu_exact(v.z); v.w = gelu_exact(v.w);
                }
                if (EPI == 3) {
                    const float4 r = *(const float4*)(res + (size_t)gm * N + gn);
                    v.x += r.x; v.y += r.y; v.z += r.z; v.w += r.w;
                }
                *(float4*)(C + (size_t)gm * N + gn) = v;
            } else {
#pragma unroll
                for (int j = 0; j < 4; j++) {
                    const int g = gn + j;
                    if (g < N) {
                        float v = acc[i][j4 * 4 + j];
                        if (EPI >= 2) v += bias[g];
                        if (EPI == 2) v = gelu_exact(v);
                        if (EPI == 3) v += res[(size_t)gm * N + g];
                        C[(size_t)gm * N + g] = v;
                    }
                }
            }
        }
    }
}

// ---------------------------------------------------------------- attention
// One wave per query row; online softmax over causal K range.
// qkv layout: [B*T, 3E]; q at h*64, k at E + h*64, v at 2E + h*64.
__global__ __launch_bounds__(256) void k_attn(const float* __restrict__ qkv,
                                              float* __restrict__ y) {
    const int wid = threadIdx.x >> 6;
    const int lane = threadIdx.x & 63;
    const int g = blockIdx.x * 4 + wid;          // row over B*H*T
    const int t = g % Tt;
    const int bh = g / Tt;
    const int h = bh % Hh;
    const int b = bh / Hh;
    const float* qp = qkv + ((size_t)(b * Tt + t) * (3 * Ee) + h * HDh);
    const float* kb = qkv + ((size_t)(b * Tt)) * (3 * Ee) + Ee + h * HDh;
    const float* vb = qkv + ((size_t)(b * Tt)) * (3 * Ee) + 2 * Ee + h * HDh;

    float q[64];
#pragma unroll
    for (int d = 0; d < 64; d += 4) {
        const float4 v4 = *(const float4*)(qp + d);
        q[d] = v4.x; q[d + 1] = v4.y; q[d + 2] = v4.z; q[d + 3] = v4.w;
    }

    float m = -INFINITY, l = 0.f, o = 0.f;   // lane owns output dim d = lane
    for (int k0 = 0; k0 <= t; k0 += 64) {
        const int kk = k0 + lane;
        float s = -INFINITY;
        if (kk <= t) {
            const float* kp = kb + (size_t)kk * (3 * Ee);
            float a = 0.f;
#pragma unroll
            for (int d = 0; d < 64; d += 4) {
                const float4 k4 = *(const float4*)(kp + d);
                a = fmaf(q[d], k4.x, a);     a = fmaf(q[d + 1], k4.y, a);
                a = fmaf(q[d + 2], k4.z, a); a = fmaf(q[d + 3], k4.w, a);
            }
            s = a * 0.125f;
        }
        float tm = s;
#pragma unroll
        for (int off = 32; off; off >>= 1) tm = fmaxf(tm, __shfl_xor(tm, off));
        const float nm = fmaxf(m, tm);                  // finite: lane 0 always valid
        const float p = (kk <= t) ? __expf(s - nm) : 0.f;
        float ps = p;
#pragma unroll
        for (int off = 32; off; off >>= 1) ps += __shfl_xor(ps, off);
        const float alpha = __expf(m - nm);             // first tile: exp(-inf)=0
        l = l * alpha + ps;
        o = o * alpha;
        const int nk = min(64, t - k0 + 1);             // uniform across wave
        const float* vp = vb + (size_t)k0 * (3 * Ee) + lane;
        for (int k = 0; k < nk; k++) {
            const float pk = __shfl(p, k);
            o = fmaf(pk, vp[(size_t)k * (3 * Ee)], o);
        }
        m = nm;
    }
    o /= l;
    y[(size_t)(b * Tt + t) * Ee + h * HDh + lane] = o;
}

// ---------------------------------------------------------------- loss
__global__ __launch_bounds__(256) void k_loss_row(const float* __restrict__ logits,
                                                  const int* __restrict__ targets,
                                                  float* __restrict__ rnll) {
    const int row = blockIdx.x;
    const float* lr = logits + (size_t)row * Vv;
    const int tid = threadIdx.x;
    float m = -INFINITY, s = 0.f;
    for (int i = tid; i < Vv; i += 256) {
        const float xv = lr[i];
        const float nm = fmaxf(m, xv);
        s = s * __expf(m - nm) + __expf(xv - nm);
        m = nm;
    }
#pragma unroll
    for (int off = 32; off; off >>= 1) {
        const float m2 = __shfl_xor(m, off);
        const float s2 = __shfl_xor(s, off);
        const float nm = fmaxf(m, m2);
        s = s * __expf(m - nm) + s2 * __expf(m2 - nm);
        m = nm;
    }
    __shared__ float mred[4], sred[4];
    const int wid = tid >> 6, lane = tid & 63;
    if (lane == 0) { mred[wid] = m; sred[wid] = s; }
    __syncthreads();
    if (tid == 0) {
        float M = mred[0], S = sred[0];
        for (int i = 1; i < 4; i++) {
            const float nm = fmaxf(M, mred[i]);
            S = S * __expf(M - nm) + sred[i] * __expf(mred[i] - nm);
            M = nm;
        }
        const float lse = M + logf(S);
        rnll[row] = lse - lr[targets[row]];
    }
}

__global__ __launch_bounds__(256) void k_loss_final(const float* __restrict__ rnll,
                                                    float* __restrict__ loss) {
    const int tid = threadIdx.x;
    float s = 0.f;
    for (int i = tid; i < BT; i += 256) s += rnll[i];
#pragma unroll
    for (int off = 32; off; off >>= 1) s += __shfl_xor(s, off);
    __shared__ float red[4];
    if ((tid & 63) == 0) red[tid >> 6] = s;
    __syncthreads();
    if (tid == 0) loss[0] = (red[0] + red[1] + red[2] + red[3]) / (float)BT;
}

// ---------------------------------------------------------------- launch
extern "C" void kernel_launch(void* const* d_in, const int* in_sizes, int n_in,
                              void* d_out, int out_size, void* d_ws, size_t ws_size,
                              hipStream_t stream) {
    const int*   idx     = (const int*)d_in[0];
    const int*   targets = (const int*)d_in[1];
    const float* wte     = (const float*)d_in[2];
    const float* wpe     = (const float*)d_in[3];
    const float* qkv_w   = (const float*)d_in[4];
    const float* proj_w  = (const float*)d_in[5];
    const float* proj_b  = (const float*)d_in[6];
    const float* ln1_g   = (const float*)d_in[7];
    const float* ln1_b   = (const float*)d_in[8];
    const float* ln2_g   = (const float*)d_in[9];
    const float* ln2_b   = (const float*)d_in[10];
    const float* fc1_w   = (const float*)d_in[11];
    const float* fc1_b   = (const float*)d_in[12];
    const float* fc2_w   = (const float*)d_in[13];
    const float* fc2_b   = (const float*)d_in[14];
    const float* lnf_g   = (const float*)d_in[15];
    const float* lnf_b   = (const float*)d_in[16];

    float* logits = (float*)d_out;
    float* loss   = logits + (size_t)BT * Vv;

    float* x    = (float*)d_ws;
    float* h    = x   + (size_t)BT * Ee;
    float* qkv  = h   + (size_t)BT * Ee;
    float* y    = qkv + (size_t)BT * 3 * Ee;
    float* h1   = y   + (size_t)BT * Ee;
    float* rnll = h1  + (size_t)BT * FFf;
    const size_t need = ((size_t)BT * (6 * Ee + FFf) + BT) * sizeof(float);
    if (ws_size < need) return;   // ws too small: leave output poisoned (diagnosable)

    k_embed<<<BT, 256, 0, stream>>>(idx, wte, wpe, x);
    for (int l = 0; l < Ll; l++) {
        k_ln<<<BT, 256, 0, stream>>>(x, ln1_g + (size_t)l * Ee, ln1_b + (size_t)l * Ee, h);
        k_gemm<0, 0><<<dim3(3 * Ee / 128, BT / 128), 256, 0, stream>>>(
            h, qkv_w + (size_t)l * Ee * 3 * Ee, nullptr, nullptr, qkv, BT, 3 * Ee, Ee);
        k_attn<<<(Bb * Hh * Tt) / 4, 256, 0, stream>>>(qkv, y);
        k_gemm<0, 3><<<dim3(Ee / 128, BT / 128), 256, 0, stream>>>(
            y, proj_w + (size_t)l * Ee * Ee, proj_b + (size_t)l * Ee, x, x, BT, Ee, Ee);
        k_ln<<<BT, 256, 0, stream>>>(x, ln2_g + (size_t)l * Ee, ln2_b + (size_t)l * Ee, h);
        k_gemm<0, 2><<<dim3(FFf / 128, BT / 128), 256, 0, stream>>>(
            h, fc1_w + (size_t)l * Ee * FFf, fc1_b + (size_t)l * FFf, nullptr, h1, BT, FFf, Ee);
        k_gemm<0, 3><<<dim3(Ee / 128, BT / 128), 256, 0, stream>>>(
            h1, fc2_w + (size_t)l * FFf * Ee, fc2_b + (size_t)l * Ee, x, x, BT, Ee, FFf);
    }
    k_ln<<<BT, 256, 0, stream>>>(x, lnf_g, lnf_b, h);
    k_gemm<1, 0><<<dim3((Vv + 127) / 128, BT / 128), 256, 0, stream>>>(
        h, wte, nullptr, nullptr, logits, BT, Vv, Ee);
    k_loss_row<<<BT, 256, 0, stream>>>(logits, targets, rnll);
    k_loss_final<<<1, 256, 0, stream>>>(rnll, loss);
}

// Round 3
// 19163.783 us; speedup vs baseline: 2.6407x; 2.6407x over previous
//
#include <hip/hip_runtime.h>
#include <math.h>

// GPT-2-ish forward: V=50257 E=1024 H=16 L=8 B=2 T=2048 HD=64 FF=4096
constexpr int Vv = 50257;
constexpr int Ee = 1024;
constexpr int Hh = 16;
constexpr int Ll = 8;
constexpr int Bb = 2;
constexpr int Tt = 2048;
constexpr int HDh = 64;
constexpr int FFf = 4096;
constexpr int BT = Bb * Tt;   // 4096 token rows

typedef __attribute__((ext_vector_type(8))) short bf16x8;
typedef __attribute__((ext_vector_type(4))) float f32x4;

__device__ __forceinline__ short f2b(float f) {   // f32 -> bf16 RNE
    union { float f; unsigned u; } c; c.f = f;
    unsigned u = c.u + 0x7fffu + ((c.u >> 16) & 1u);
    return (short)(u >> 16);
}

// async 16B global->LDS (dest = wave-uniform base + lane*16)
__device__ __forceinline__ void g2l16(void* lds, const void* g) {
    __builtin_amdgcn_global_load_lds(
        (const __attribute__((address_space(1))) void*)g,
        (__attribute__((address_space(3))) void*)lds, 16, 0, 0);
}

__device__ __forceinline__ float gelu_exact(float v) {
    return 0.5f * v * (1.0f + erff(v * 0.70710678118654752f));
}

// ---------------------------------------------------------------- embedding
__global__ __launch_bounds__(256) void k_embed(const int* __restrict__ idx,
                                               const float* __restrict__ wte,
                                               const float* __restrict__ wpe,
                                               float* __restrict__ x) {
    const int row = blockIdx.x;
    const int t = row % Tt;
    const int tok = idx[row];
    const int c = threadIdx.x * 4;
    const float4 a = *(const float4*)(wte + (size_t)tok * Ee + c);
    const float4 b = *(const float4*)(wpe + (size_t)t * Ee + c);
    *(float4*)(x + (size_t)row * Ee + c) =
        make_float4(a.x + b.x, a.y + b.y, a.z + b.z, a.w + b.w);
}

// ------------------------------------------------- layernorm (f32 in, bf16 out)
__global__ __launch_bounds__(256) void k_ln(const float* __restrict__ x,
                                            const float* __restrict__ g,
                                            const float* __restrict__ b,
                                            short* __restrict__ out) {
    const int row = blockIdx.x;
    const int tid = threadIdx.x;
    const float4 v = *(const float4*)(x + (size_t)row * Ee + tid * 4);
    float s  = v.x + v.y + v.z + v.w;
    float ss = v.x * v.x + v.y * v.y + v.z * v.z + v.w * v.w;
#pragma unroll
    for (int off = 32; off; off >>= 1) {
        s  += __shfl_down(s, off);
        ss += __shfl_down(ss, off);
    }
    __shared__ float red[8];
    const int wid = tid >> 6, lane = tid & 63;
    if (lane == 0) { red[wid] = s; red[4 + wid] = ss; }
    __syncthreads();
    const float S  = red[0] + red[1] + red[2] + red[3];
    const float SS = red[4] + red[5] + red[6] + red[7];
    const float mean = S * (1.f / Ee);
    const float var  = SS * (1.f / Ee) - mean * mean;
    const float inv  = rsqrtf(var + 1e-5f);
    const float4 gg = *(const float4*)(g + tid * 4);
    const float4 bb = *(const float4*)(b + tid * 4);
    short4 o;
    o.x = f2b((v.x - mean) * inv * gg.x + bb.x);
    o.y = f2b((v.y - mean) * inv * gg.y + bb.y);
    o.z = f2b((v.z - mean) * inv * gg.z + bb.z);
    o.w = f2b((v.w - mean) * inv * gg.w + bb.w);
    *(short4*)(out + (size_t)row * Ee + tid * 4) = o;
}

// ---------------------------- weight transpose+convert: w[K][N] f32 -> o[N][K] bf16
__global__ __launch_bounds__(256) void k_wT(const float* __restrict__ w,
                                            short* __restrict__ o, int K, int N) {
    __shared__ short t[32][33];
    const int n0 = blockIdx.x * 32, k0 = blockIdx.y * 32;
    const int tid = threadIdx.x;
    {
        const int k = tid >> 3, n4 = (tid & 7) * 4;
        const float4 v = *(const float4*)(w + (size_t)(k0 + k) * N + n0 + n4);
        t[n4 + 0][k] = f2b(v.x); t[n4 + 1][k] = f2b(v.y);
        t[n4 + 2][k] = f2b(v.z); t[n4 + 3][k] = f2b(v.w);
    }
    __syncthreads();
    {
        const int n = tid >> 3, k4 = (tid & 7) * 4;
        short4 s;
        s.x = t[n][k4]; s.y = t[n][k4 + 1]; s.z = t[n][k4 + 2]; s.w = t[n][k4 + 3];
        *(short4*)(o + (size_t)(n0 + n) * K + k0 + k4) = s;
    }
}

// ---------------------------------------------------------------- MFMA GEMM
// C[M,N] = A[M,K](bf16) @ B + epilogue.  B is [N][K]:
//   BSRC=0: bf16 (pre-transposed weight scratch) -> global_load_lds
//   BSRC=1: f32 (wte) -> reg-stage with convert
// EPI: 0 none, 2 bias+GELU, 3 bias+residual.  OT: float or short(bf16).
__device__ __forceinline__ void st_c(float* C, size_t i, float v) { C[i] = v; }
__device__ __forceinline__ void st_c(short* C, size_t i, float v) { C[i] = f2b(v); }

template <int BSRC, int EPI, typename OT>
__global__ __launch_bounds__(256) void k_gemm(const short* __restrict__ A,
                                              const void* __restrict__ Bv,
                                              const float* __restrict__ bias,
                                              const float* __restrict__ res,
                                              OT* __restrict__ C,
                                              int M, int N, int K) {
    __shared__ short As[128 * 32];
    __shared__ short Bs[128 * 32];
    const int tid = threadIdx.x, w = tid >> 6, ln = tid & 63;
    const int m0 = blockIdx.x * 128, n0 = blockIdx.y * 128;
    const int wr = w >> 1, wc = w & 1;

    f32x4 zero = {0.f, 0.f, 0.f, 0.f};
    f32x4 acc[4][4];
#pragma unroll
    for (int i = 0; i < 4; i++)
#pragma unroll
        for (int j = 0; j < 4; j++) acc[i][j] = zero;

    const int srow = w * 32 + (ln >> 2);     // staging row within tile (wave part)
    const int scol = (ln & 3) * 8;           // staging k offset (8 bf16 = 16B)

    for (int k0 = 0; k0 < K; k0 += 32) {
        __syncthreads();
        // --- stage A (bf16, [M][K]) via async direct-to-LDS
        g2l16(&As[(w * 32 + 0) * 32],  A + (size_t)(m0 + srow) * K + k0 + scol);
        g2l16(&As[(w * 32 + 16) * 32], A + (size_t)(m0 + srow + 16) * K + k0 + scol);
        if (BSRC == 0) {
            const short* Bp = (const short*)Bv;
            g2l16(&Bs[(w * 32 + 0) * 32],  Bp + (size_t)(n0 + srow) * K + k0 + scol);
            g2l16(&Bs[(w * 32 + 16) * 32], Bp + (size_t)(n0 + srow + 16) * K + k0 + scol);
        } else {
            const float* Bp = (const float*)Bv;
            const int nn = tid >> 1;
            const int nr = (n0 + nn < N) ? (n0 + nn) : (N - 1);
            const int kc = (tid & 1) * 16;
            const float* p = Bp + (size_t)nr * K + k0 + kc;
            const float4 x0 = *(const float4*)(p + 0);
            const float4 x1 = *(const float4*)(p + 4);
            const float4 x2 = *(const float4*)(p + 8);
            const float4 x3 = *(const float4*)(p + 12);
            bf16x8 p0 = {f2b(x0.x), f2b(x0.y), f2b(x0.z), f2b(x0.w),
                         f2b(x1.x), f2b(x1.y), f2b(x1.z), f2b(x1.w)};
            bf16x8 p1 = {f2b(x2.x), f2b(x2.y), f2b(x2.z), f2b(x2.w),
                         f2b(x3.x), f2b(x3.y), f2b(x3.z), f2b(x3.w)};
            *(bf16x8*)&Bs[nn * 32 + kc]     = p0;
            *(bf16x8*)&Bs[nn * 32 + kc + 8] = p1;
        }
        __syncthreads();   // drains vmcnt (incl. global_load_lds) + lgkm
        // --- fragments + MFMA
        bf16x8 af[4], bfv[4];
#pragma unroll
        for (int i = 0; i < 4; i++) {
            af[i]  = *(bf16x8*)&As[(wr * 64 + i * 16 + (ln & 15)) * 32 + (ln >> 4) * 8];
            bfv[i] = *(bf16x8*)&Bs[(wc * 64 + i * 16 + (ln & 15)) * 32 + (ln >> 4) * 8];
        }
#pragma unroll
        for (int i = 0; i < 4; i++)
#pragma unroll
            for (int j = 0; j < 4; j++)
                acc[i][j] = __builtin_amdgcn_mfma_f32_16x16x32_bf16(
                    af[i], bfv[j], acc[i][j], 0, 0, 0);
    }

    // --- epilogue: C/D layout col=lane&15, row=(lane>>4)*4+reg  [m89]
#pragma unroll
    for (int j = 0; j < 4; j++) {
        const int gcol = n0 + wc * 64 + j * 16 + (ln & 15);
        if (gcol < N) {
            const float bv = (EPI >= 2) ? bias[gcol] : 0.f;
#pragma unroll
            for (int i = 0; i < 4; i++) {
#pragma unroll
                for (int r = 0; r < 4; r++) {
                    const int grow = m0 + wr * 64 + i * 16 + (ln >> 4) * 4 + r;
                    float v = acc[i][j][r] + bv;
                    if (EPI == 2) v = gelu_exact(v);
                    if (EPI == 3) v += res[(size_t)grow * N + gcol];
                    st_c(C, (size_t)grow * N + gcol, v);
                }
            }
        }
    }
}

// ---------------------------------------------------------------- attention
// Block = one (b, h, 64-q-row chunk). 4 waves x 16 rows. K/V tiles in LDS,
// online softmax per row, PV via register P + shfl broadcast. y out bf16.
__global__ __launch_bounds__(256) void k_attn(const float* __restrict__ qkv,
                                              short* __restrict__ y) {
    __shared__ float Q[64][68];
    __shared__ float Kl[64][68];
    __shared__ float Vl[64][64];
    const int tid = threadIdx.x, w = tid >> 6, ln = tid & 63;
    const int q0 = blockIdx.x * 64, h = blockIdx.y, b = blockIdx.z;
    const size_t base = ((size_t)b * Tt) * (3 * Ee) + h * HDh;

    {   // stage Q (scaled by 1/8)
        const int r = tid >> 2, s4 = tid & 3;
        const float* qp = qkv + base + (size_t)(q0 + r) * (3 * Ee);
#pragma unroll
        for (int p = 0; p < 4; p++) {
            const int d = s4 * 16 + p * 4;
            const float4 v = *(const float4*)(qp + d);
            Q[r][d] = v.x * 0.125f; Q[r][d + 1] = v.y * 0.125f;
            Q[r][d + 2] = v.z * 0.125f; Q[r][d + 3] = v.w * 0.125f;
        }
    }
    float m[16], l[16], o[16];
#pragma unroll
    for (int r = 0; r < 16; r++) { m[r] = -INFINITY; l[r] = 0.f; o[r] = 0.f; }

    const int nt = blockIdx.x + 1;
    for (int j = 0; j < nt; j++) {
        const int kb = j * 64;
        __syncthreads();          // prev tile fully consumed (also covers Q stage)
        {   // stage K, V tiles
            const int r = tid >> 2, s4 = tid & 3;
            const float* kp = qkv + base + Ee     + (size_t)(kb + r) * (3 * Ee);
            const float* vp = qkv + base + 2 * Ee + (size_t)(kb + r) * (3 * Ee);
#pragma unroll
            for (int p = 0; p < 4; p++) {
                const int d = s4 * 16 + p * 4;
                *(float4*)&Kl[r][d] = *(const float4*)(kp + d);
                *(float4*)&Vl[r][d] = *(const float4*)(vp + d);
            }
        }
        __syncthreads();

        float p_reg[16];
#pragma unroll
        for (int r = 0; r < 16; r++) {
            const int qr = q0 + w * 16 + r;
            const bool valid = (kb + ln) <= qr;
            float s_ = 0.f;
#pragma unroll
            for (int d = 0; d < 64; d += 4) {
                const float4 qv = *(const float4*)&Q[w * 16 + r][d];
                const float4 kv = *(const float4*)&Kl[ln][d];
                s_ = fmaf(qv.x, kv.x, s_); s_ = fmaf(qv.y, kv.y, s_);
                s_ = fmaf(qv.z, kv.z, s_); s_ = fmaf(qv.w, kv.w, s_);
            }
            s_ = valid ? s_ : -INFINITY;
            float tm = s_;
#pragma unroll
            for (int off = 32; off; off >>= 1) tm = fmaxf(tm, __shfl_xor(tm, off));
            const float nm = fmaxf(m[r], tm);          // finite: lane0 always valid
            const float pv = valid ? __expf(s_ - nm) : 0.f;
            float ps = pv;
#pragma unroll
            for (int off = 32; off; off >>= 1) ps += __shfl_xor(ps, off);
            const float alpha = __expf(m[r] - nm);
            l[r] = l[r] * alpha + ps;
            o[r] *= alpha;
            m[r] = nm;
            p_reg[r] = pv;
        }
        for (int k = 0; k < 64; k++) {
            const float vk = Vl[k][ln];
#pragma unroll
            for (int r = 0; r < 16; r++)
                o[r] = fmaf(__shfl(p_reg[r], k), vk, o[r]);
        }
    }
#pragma unroll
    for (int r = 0; r < 16; r++) {
        const int qr = q0 + w * 16 + r;
        y[((size_t)(b * Tt + qr)) * Ee + h * HDh + ln] = f2b(o[r] / l[r]);
    }
}

// ---------------------------------------------------------------- loss
__global__ __launch_bounds__(256) void k_loss_row(const float* __restrict__ logits,
                                                  const int* __restrict__ targets,
                                                  float* __restrict__ rnll) {
    const int row = blockIdx.x;
    const float* lr = logits + (size_t)row * Vv;
    const int tid = threadIdx.x;
    float m = -INFINITY, s = 0.f;
    for (int i = tid; i < Vv; i += 256) {
        const float xv = lr[i];
        const float nm = fmaxf(m, xv);
        s = s * __expf(m - nm) + __expf(xv - nm);
        m = nm;
    }
#pragma unroll
    for (int off = 32; off; off >>= 1) {
        const float m2 = __shfl_xor(m, off);
        const float s2 = __shfl_xor(s, off);
        const float nm = fmaxf(m, m2);
        s = s * __expf(m - nm) + s2 * __expf(m2 - nm);
        m = nm;
    }
    __shared__ float mred[4], sred[4];
    const int wid = tid >> 6, lane = tid & 63;
    if (lane == 0) { mred[wid] = m; sred[wid] = s; }
    __syncthreads();
    if (tid == 0) {
        float M = mred[0], S = sred[0];
        for (int i = 1; i < 4; i++) {
            const float nm = fmaxf(M, mred[i]);
            S = S * __expf(M - nm) + sred[i] * __expf(mred[i] - nm);
            M = nm;
        }
        rnll[row] = (M + logf(S)) - lr[targets[row]];
    }
}

__global__ __launch_bounds__(256) void k_loss_final(const float* __restrict__ rnll,
                                                    float* __restrict__ loss) {
    const int tid = threadIdx.x;
    float s = 0.f;
    for (int i = tid; i < BT; i += 256) s += rnll[i];
#pragma unroll
    for (int off = 32; off; off >>= 1) s += __shfl_xor(s, off);
    __shared__ float red[4];
    if ((tid & 63) == 0) red[tid >> 6] = s;
    __syncthreads();
    if (tid == 0) loss[0] = (red[0] + red[1] + red[2] + red[3]) / (float)BT;
}

// ---------------------------------------------------------------- launch
extern "C" void kernel_launch(void* const* d_in, const int* in_sizes, int n_in,
                              void* d_out, int out_size, void* d_ws, size_t ws_size,
                              hipStream_t stream) {
    const int*   idx     = (const int*)d_in[0];
    const int*   targets = (const int*)d_in[1];
    const float* wte     = (const float*)d_in[2];
    const float* wpe     = (const float*)d_in[3];
    const float* qkv_w   = (const float*)d_in[4];
    const float* proj_w  = (const float*)d_in[5];
    const float* proj_b  = (const float*)d_in[6];
    const float* ln1_g   = (const float*)d_in[7];
    const float* ln1_b   = (const float*)d_in[8];
    const float* ln2_g   = (const float*)d_in[9];
    const float* ln2_b   = (const float*)d_in[10];
    const float* fc1_w   = (const float*)d_in[11];
    const float* fc1_b   = (const float*)d_in[12];
    const float* fc2_w   = (const float*)d_in[13];
    const float* fc2_b   = (const float*)d_in[14];
    const float* lnf_g   = (const float*)d_in[15];
    const float* lnf_b   = (const float*)d_in[16];

    float* logits = (float*)d_out;
    float* loss   = logits + (size_t)BT * Vv;

    float* x     = (float*)d_ws;
    float* qkvb  = x + (size_t)BT * Ee;
    float* rnll  = qkvb + (size_t)BT * 3 * Ee;
    short* h     = (short*)(rnll + BT);
    short* y     = h  + (size_t)BT * Ee;
    short* h1    = y  + (size_t)BT * Ee;
    short* wT    = h1 + (size_t)BT * FFf;
    const size_t need = ((size_t)BT * (4 * Ee) + BT) * sizeof(float)
                      + ((size_t)BT * (2 * Ee + FFf) + (size_t)FFf * Ee) * sizeof(short);
    if (ws_size < need) return;

    k_embed<<<BT, 256, 0, stream>>>(idx, wte, wpe, x);
    for (int l = 0; l < Ll; l++) {
        k_ln<<<BT, 256, 0, stream>>>(x, ln1_g + (size_t)l * Ee, ln1_b + (size_t)l * Ee, h);
        k_wT<<<dim3(3 * Ee / 32, Ee / 32), 256, 0, stream>>>(
            qkv_w + (size_t)l * Ee * 3 * Ee, wT, Ee, 3 * Ee);
        k_gemm<0, 0, float><<<dim3(BT / 128, 3 * Ee / 128), 256, 0, stream>>>(
            h, wT, nullptr, nullptr, qkvb, BT, 3 * Ee, Ee);
        k_attn<<<dim3(Tt / 64, Hh, Bb), 256, 0, stream>>>(qkvb, y);
        k_wT<<<dim3(Ee / 32, Ee / 32), 256, 0, stream>>>(
            proj_w + (size_t)l * Ee * Ee, wT, Ee, Ee);
        k_gemm<0, 3, float><<<dim3(BT / 128, Ee / 128), 256, 0, stream>>>(
            y, wT, proj_b + (size_t)l * Ee, x, x, BT, Ee, Ee);
        k_ln<<<BT, 256, 0, stream>>>(x, ln2_g + (size_t)l * Ee, ln2_b + (size_t)l * Ee, h);
        k_wT<<<dim3(FFf / 32, Ee / 32), 256, 0, stream>>>(
            fc1_w + (size_t)l * Ee * FFf, wT, Ee, FFf);
        k_gemm<0, 2, short><<<dim3(BT / 128, FFf / 128), 256, 0, stream>>>(
            h, wT, fc1_b + (size_t)l * FFf, nullptr, h1, BT, FFf, Ee);
        k_wT<<<dim3(Ee / 32, FFf / 32), 256, 0, stream>>>(
            fc2_w + (size_t)l * FFf * Ee, wT, FFf, Ee);
        k_gemm<0, 3, float><<<dim3(BT / 128, Ee / 128), 256, 0, stream>>>(
            h1, wT, fc2_b + (size_t)l * Ee, x, x, BT, Ee, FFf);
    }
    k_ln<<<BT, 256, 0, stream>>>(x, lnf_g, lnf_b, h);
    k_gemm<1, 0, float><<<dim3(BT / 128, (Vv + 127) / 128), 256, 0, stream>>>(
        h, wte, nullptr, nullptr, logits, BT, Vv, Ee);
    k_loss_row<<<BT, 256, 0, stream>>>(logits, targets, rnll);
    k_loss_final<<<1, 256, 0, stream>>>(rnll, loss);
}

// Round 5
// 4382.509 us; speedup vs baseline: 11.5472x; 4.3728x over previous
//
#include <hip/hip_runtime.h>
#include <math.h>

// GPT-2-ish forward: V=50257 E=1024 H=16 L=8 B=2 T=2048 HD=64 FF=4096
constexpr int Vv = 50257;
constexpr int Ee = 1024;
constexpr int Hh = 16;
constexpr int Ll = 8;
constexpr int Bb = 2;
constexpr int Tt = 2048;
constexpr int HDh = 64;
constexpr int FFf = 4096;
constexpr int BT = Bb * Tt;   // 4096 token rows

typedef __attribute__((ext_vector_type(8))) short bf16x8;
typedef __attribute__((ext_vector_type(4))) float f32x4;

__device__ __forceinline__ short f2b(float f) {   // f32 -> bf16 RNE
    union { float f; unsigned u; } c; c.f = f;
    unsigned u = c.u + 0x7fffu + ((c.u >> 16) & 1u);
    return (short)(u >> 16);
}

// async 16B global->LDS (dest = wave-uniform base + lane*16)
__device__ __forceinline__ void g2l16(void* lds, const void* g) {
    __builtin_amdgcn_global_load_lds(
        (const __attribute__((address_space(1))) void*)g,
        (__attribute__((address_space(3))) void*)lds, 16, 0, 0);
}

__device__ __forceinline__ float gelu_exact(float v) {
    return 0.5f * v * (1.0f + erff(v * 0.70710678118654752f));
}

// ---------------------------------------------------------------- embedding
__global__ __launch_bounds__(256) void k_embed(const int* __restrict__ idx,
                                               const float* __restrict__ wte,
                                               const float* __restrict__ wpe,
                                               float* __restrict__ x) {
    const int row = blockIdx.x;
    const int t = row % Tt;
    const int tok = idx[row];
    const int c = threadIdx.x * 4;
    const float4 a = *(const float4*)(wte + (size_t)tok * Ee + c);
    const float4 b = *(const float4*)(wpe + (size_t)t * Ee + c);
    *(float4*)(x + (size_t)row * Ee + c) =
        make_float4(a.x + b.x, a.y + b.y, a.z + b.z, a.w + b.w);
}

// ------------------------------------------------- layernorm (f32 in, bf16 out)
__global__ __launch_bounds__(256) void k_ln(const float* __restrict__ x,
                                            const float* __restrict__ g,
                                            const float* __restrict__ b,
                                            short* __restrict__ out) {
    const int row = blockIdx.x;
    const int tid = threadIdx.x;
    const float4 v = *(const float4*)(x + (size_t)row * Ee + tid * 4);
    float s  = v.x + v.y + v.z + v.w;
    float ss = v.x * v.x + v.y * v.y + v.z * v.z + v.w * v.w;
#pragma unroll
    for (int off = 32; off; off >>= 1) {
        s  += __shfl_down(s, off);
        ss += __shfl_down(ss, off);
    }
    __shared__ float red[8];
    const int wid = tid >> 6, lane = tid & 63;
    if (lane == 0) { red[wid] = s; red[4 + wid] = ss; }
    __syncthreads();
    const float S  = red[0] + red[1] + red[2] + red[3];
    const float SS = red[4] + red[5] + red[6] + red[7];
    const float mean = S * (1.f / Ee);
    const float var  = SS * (1.f / Ee) - mean * mean;
    const float inv  = rsqrtf(var + 1e-5f);
    const float4 gg = *(const float4*)(g + tid * 4);
    const float4 bb = *(const float4*)(b + tid * 4);
    short4 o;
    o.x = f2b((v.x - mean) * inv * gg.x + bb.x);
    o.y = f2b((v.y - mean) * inv * gg.y + bb.y);
    o.z = f2b((v.z - mean) * inv * gg.z + bb.z);
    o.w = f2b((v.w - mean) * inv * gg.w + bb.w);
    *(short4*)(out + (size_t)row * Ee + tid * 4) = o;
}

// ---------------------------- weight transpose+convert: w[K][N] f32 -> o[N][K] bf16
__global__ __launch_bounds__(256) void k_wT(const float* __restrict__ w,
                                            short* __restrict__ o, int K, int N) {
    __shared__ short t[32][33];
    const int n0 = blockIdx.x * 32, k0 = blockIdx.y * 32;
    const int tid = threadIdx.x;
    {
        const int k = tid >> 3, n4 = (tid & 7) * 4;
        const float4 v = *(const float4*)(w + (size_t)(k0 + k) * N + n0 + n4);
        t[n4 + 0][k] = f2b(v.x); t[n4 + 1][k] = f2b(v.y);
        t[n4 + 2][k] = f2b(v.z); t[n4 + 3][k] = f2b(v.w);
    }
    __syncthreads();
    {
        const int n = tid >> 3, k4 = (tid & 7) * 4;
        short4 s;
        s.x = t[n][k4]; s.y = t[n][k4 + 1]; s.z = t[n][k4 + 2]; s.w = t[n][k4 + 3];
        *(short4*)(o + (size_t)(n0 + n) * K + k0 + k4) = s;
    }
}

// ---------------------------------------------------------------- MFMA GEMM
// C[M,N] = A[M,K](bf16) @ B + epilogue.  B is [N][K]:
//   BSRC=0: bf16 (pre-transposed weight scratch) -> global_load_lds
//   BSRC=1: f32 (wte) -> reg-stage with convert
// EPI: 0 none, 2 bias+GELU, 3 bias+residual.  OT: float or short(bf16).
__device__ __forceinline__ void st_c(float* C, size_t i, float v) { C[i] = v; }
__device__ __forceinline__ void st_c(short* C, size_t i, float v) { C[i] = f2b(v); }

template <int BSRC, int EPI, typename OT>
__global__ __launch_bounds__(256) void k_gemm(const short* __restrict__ A,
                                              const void* __restrict__ Bv,
                                              const float* __restrict__ bias,
                                              const float* __restrict__ res,
                                              OT* __restrict__ C,
                                              int M, int N, int K) {
    __shared__ short As[128 * 32];
    __shared__ short Bs[128 * 32];
    const int tid = threadIdx.x, w = tid >> 6, ln = tid & 63;
    const int m0 = blockIdx.x * 128, n0 = blockIdx.y * 128;
    const int wr = w >> 1, wc = w & 1;

    f32x4 zero = {0.f, 0.f, 0.f, 0.f};
    f32x4 acc[4][4];
#pragma unroll
    for (int i = 0; i < 4; i++)
#pragma unroll
        for (int j = 0; j < 4; j++) acc[i][j] = zero;

    const int srow = w * 32 + (ln >> 2);     // staging row within tile (wave part)
    const int scol = (ln & 3) * 8;           // staging k offset (8 bf16 = 16B)

    for (int k0 = 0; k0 < K; k0 += 32) {
        __syncthreads();
        // --- stage A (bf16, [M][K]) via async direct-to-LDS
        g2l16(&As[(w * 32 + 0) * 32],  A + (size_t)(m0 + srow) * K + k0 + scol);
        g2l16(&As[(w * 32 + 16) * 32], A + (size_t)(m0 + srow + 16) * K + k0 + scol);
        if (BSRC == 0) {
            const short* Bp = (const short*)Bv;
            g2l16(&Bs[(w * 32 + 0) * 32],  Bp + (size_t)(n0 + srow) * K + k0 + scol);
            g2l16(&Bs[(w * 32 + 16) * 32], Bp + (size_t)(n0 + srow + 16) * K + k0 + scol);
        } else {
            const float* Bp = (const float*)Bv;
            const int nn = tid >> 1;
            const int nr = (n0 + nn < N) ? (n0 + nn) : (N - 1);
            const int kc = (tid & 1) * 16;
            const float* p = Bp + (size_t)nr * K + k0 + kc;
            const float4 x0 = *(const float4*)(p + 0);
            const float4 x1 = *(const float4*)(p + 4);
            const float4 x2 = *(const float4*)(p + 8);
            const float4 x3 = *(const float4*)(p + 12);
            bf16x8 p0 = {f2b(x0.x), f2b(x0.y), f2b(x0.z), f2b(x0.w),
                         f2b(x1.x), f2b(x1.y), f2b(x1.z), f2b(x1.w)};
            bf16x8 p1 = {f2b(x2.x), f2b(x2.y), f2b(x2.z), f2b(x2.w),
                         f2b(x3.x), f2b(x3.y), f2b(x3.z), f2b(x3.w)};
            *(bf16x8*)&Bs[nn * 32 + kc]     = p0;
            *(bf16x8*)&Bs[nn * 32 + kc + 8] = p1;
        }
        __syncthreads();   // drains vmcnt (incl. global_load_lds) + lgkm
        // --- fragments + MFMA
        bf16x8 af[4], bfv[4];
#pragma unroll
        for (int i = 0; i < 4; i++) {
            af[i]  = *(bf16x8*)&As[(wr * 64 + i * 16 + (ln & 15)) * 32 + (ln >> 4) * 8];
            bfv[i] = *(bf16x8*)&Bs[(wc * 64 + i * 16 + (ln & 15)) * 32 + (ln >> 4) * 8];
        }
#pragma unroll
        for (int i = 0; i < 4; i++)
#pragma unroll
            for (int j = 0; j < 4; j++)
                acc[i][j] = __builtin_amdgcn_mfma_f32_16x16x32_bf16(
                    af[i], bfv[j], acc[i][j], 0, 0, 0);
    }

    // --- epilogue: C/D layout col=lane&15, row=(lane>>4)*4+reg  [m89]
#pragma unroll
    for (int j = 0; j < 4; j++) {
        const int gcol = n0 + wc * 64 + j * 16 + (ln & 15);
        if (gcol < N) {
            const float bv = (EPI >= 2) ? bias[gcol] : 0.f;
#pragma unroll
            for (int i = 0; i < 4; i++) {
#pragma unroll
                for (int r = 0; r < 4; r++) {
                    const int grow = m0 + wr * 64 + i * 16 + (ln >> 4) * 4 + r;
                    float v = acc[i][j][r] + bv;
                    if (EPI == 2) v = gelu_exact(v);
                    if (EPI == 3) v += res[(size_t)grow * N + gcol];
                    st_c(C, (size_t)grow * N + gcol, v);
                }
            }
        }
    }
}

// ---------------------------------------------------------------- attention
// MFMA flash attention. Block = (b, h, 64 q-rows); 4 waves x 16 q-rows.
// qkv is bf16 [B*T][3E]; q at h*64, k at E+h*64, v at 2E+h*64. Out y bf16.
// MFMA convention (verified by k_gemm): D = A[m][k] . B[n][k]^T,
//   A/B frag: elem (row=ln&15, k=(ln>>4)*8+j); D: row=(ln>>4)*4+r, col=ln&15.
__global__ __launch_bounds__(256) void k_attn(const short* __restrict__ qkv,
                                              short* __restrict__ y) {
    __shared__ short Kl[64][72];      // [key][d]   (pad 8 -> 2-way-free b128 reads)
    __shared__ short Vt[64][72];      // [d][key]   (transposed V)
    __shared__ short Pl[4][16][72];   // per-wave P [q][key]
    const int tid = threadIdx.x, w = tid >> 6, ln = tid & 63;
    const int q0 = blockIdx.x * 64, h = blockIdx.y, b = blockIdx.z;
    const size_t base = ((size_t)b * Tt) * (3 * Ee) + h * HDh;

    // Q fragments (A-operand), held all kernel: row = ln&15 of this wave's 16 rows
    bf16x8 qf[2];
    {
        const int qr = q0 + w * 16 + (ln & 15);
        const short* qp = qkv + base + (size_t)qr * (3 * Ee) + (ln >> 4) * 8;
        qf[0] = *(const bf16x8*)(qp);
        qf[1] = *(const bf16x8*)(qp + 32);
    }

    f32x4 zero = {0.f, 0.f, 0.f, 0.f};
    f32x4 oc[4];                       // O tile 16q x 64d: oc[db], col=db*16+(ln&15)
#pragma unroll
    for (int i = 0; i < 4; i++) oc[i] = zero;
    float mx[4], ls[4];                // per row (ln>>4)*4+r
#pragma unroll
    for (int r = 0; r < 4; r++) { mx[r] = -INFINITY; ls[r] = 0.f; }

    const int nt = blockIdx.x + 1;
    for (int j = 0; j < nt; j++) {
        const int kb = j * 64;
        __syncthreads();               // all waves done reading prev K/V tile
        {   // stage K [kk][d] and V transposed [d][kk]
            const int r = tid >> 2, d0 = (tid & 3) * 16;
            const short* kp = qkv + base + Ee     + (size_t)(kb + r) * (3 * Ee) + d0;
            const short* vp = qkv + base + 2 * Ee + (size_t)(kb + r) * (3 * Ee) + d0;
            *(bf16x8*)&Kl[r][d0]     = *(const bf16x8*)(kp);
            *(bf16x8*)&Kl[r][d0 + 8] = *(const bf16x8*)(kp + 8);
            bf16x8 v0 = *(const bf16x8*)(vp);
            bf16x8 v1 = *(const bf16x8*)(vp + 8);
#pragma unroll
            for (int p = 0; p < 8; p++) Vt[d0 + p][r] = v0[p];
#pragma unroll
            for (int p = 0; p < 8; p++) Vt[d0 + 8 + p][r] = v1[p];
        }
        __syncthreads();

        // --- S = Q K^T  (16q x 64k as 4 col-blocks)
        f32x4 sc[4];
#pragma unroll
        for (int kcb = 0; kcb < 4; kcb++) {
            const int krow = kcb * 16 + (ln & 15);
            bf16x8 kf0 = *(bf16x8*)&Kl[krow][(ln >> 4) * 8];
            bf16x8 kf1 = *(bf16x8*)&Kl[krow][(ln >> 4) * 8 + 32];
            f32x4 s = __builtin_amdgcn_mfma_f32_16x16x32_bf16(qf[0], kf0, zero, 0, 0, 0);
            sc[kcb]  = __builtin_amdgcn_mfma_f32_16x16x32_bf16(qf[1], kf1, s, 0, 0, 0);
        }
        // --- mask + online softmax (row = (ln>>4)*4+r, col = kb+kcb*16+(ln&15))
        float pv[4][4];                // [kcb][r]
        float tmv[4] = {-INFINITY, -INFINITY, -INFINITY, -INFINITY};
#pragma unroll
        for (int kcb = 0; kcb < 4; kcb++) {
            const int col = kb + kcb * 16 + (ln & 15);
#pragma unroll
            for (int r = 0; r < 4; r++) {
                const int qr = q0 + w * 16 + (ln >> 4) * 4 + r;
                const float sv = (col <= qr) ? sc[kcb][r] * 0.125f : -INFINITY;
                pv[kcb][r] = sv;
                tmv[r] = fmaxf(tmv[r], sv);
            }
        }
#pragma unroll
        for (int off = 1; off < 16; off <<= 1)
#pragma unroll
            for (int r = 0; r < 4; r++) tmv[r] = fmaxf(tmv[r], __shfl_xor(tmv[r], off));
        float rs[4];
#pragma unroll
        for (int r = 0; r < 4; r++) {
            const float nm = fmaxf(mx[r], tmv[r]);      // finite: col=kb always valid
            const float alpha = __expf(mx[r] - nm);     // first tile: exp(-inf)=0
            mx[r] = nm;
            float acc_s = 0.f;
#pragma unroll
            for (int kcb = 0; kcb < 4; kcb++) {
                const float e = __expf(pv[kcb][r] - nm);   // -inf -> 0
                pv[kcb][r] = e;
                acc_s += e;
            }
            rs[r] = acc_s;
            ls[r] *= alpha;
#pragma unroll
            for (int db = 0; db < 4; db++) oc[db][r] *= alpha;
        }
#pragma unroll
        for (int off = 1; off < 16; off <<= 1)
#pragma unroll
            for (int r = 0; r < 4; r++) rs[r] += __shfl_xor(rs[r], off);
#pragma unroll
        for (int r = 0; r < 4; r++) ls[r] += rs[r];
        // --- P -> LDS (bf16), reshape to A-fragments (same-wave dep: lgkmcnt)
#pragma unroll
        for (int kcb = 0; kcb < 4; kcb++)
#pragma unroll
            for (int r = 0; r < 4; r++)
                Pl[w][(ln >> 4) * 4 + r][kcb * 16 + (ln & 15)] = f2b(pv[kcb][r]);
        bf16x8 pf0 = *(bf16x8*)&Pl[w][ln & 15][(ln >> 4) * 8];
        bf16x8 pf1 = *(bf16x8*)&Pl[w][ln & 15][(ln >> 4) * 8 + 32];
        // --- O += P V   (B-operand = Vt[d][kk])
#pragma unroll
        for (int db = 0; db < 4; db++) {
            const int drow = db * 16 + (ln & 15);
            bf16x8 vf0 = *(bf16x8*)&Vt[drow][(ln >> 4) * 8];
            bf16x8 vf1 = *(bf16x8*)&Vt[drow][(ln >> 4) * 8 + 32];
            oc[db] = __builtin_amdgcn_mfma_f32_16x16x32_bf16(pf0, vf0, oc[db], 0, 0, 0);
            oc[db] = __builtin_amdgcn_mfma_f32_16x16x32_bf16(pf1, vf1, oc[db], 0, 0, 0);
        }
    }
    // --- epilogue
#pragma unroll
    for (int r = 0; r < 4; r++) {
        const int qr = q0 + w * 16 + (ln >> 4) * 4 + r;
        const float inv = 1.f / ls[r];
#pragma unroll
        for (int db = 0; db < 4; db++)
            y[(size_t)(b * Tt + qr) * Ee + h * HDh + db * 16 + (ln & 15)] =
                f2b(oc[db][r] * inv);
    }
}

// ---------------------------------------------------------------- loss
__global__ __launch_bounds__(256) void k_loss_row(const float* __restrict__ logits,
                                                  const int* __restrict__ targets,
                                                  float* __restrict__ rnll) {
    const int row = blockIdx.x;
    const float* lr = logits + (size_t)row * Vv;
    const int tid = threadIdx.x;
    float m = -INFINITY, s = 0.f;
    for (int i = tid; i < Vv; i += 256) {
        const float xv = lr[i];
        const float nm = fmaxf(m, xv);
        s = s * __expf(m - nm) + __expf(xv - nm);
        m = nm;
    }
#pragma unroll
    for (int off = 32; off; off >>= 1) {
        const float m2 = __shfl_xor(m, off);
        const float s2 = __shfl_xor(s, off);
        const float nm = fmaxf(m, m2);
        s = s * __expf(m - nm) + s2 * __expf(m2 - nm);
        m = nm;
    }
    __shared__ float mred[4], sred[4];
    const int wid = tid >> 6, lane = tid & 63;
    if (lane == 0) { mred[wid] = m; sred[wid] = s; }
    __syncthreads();
    if (tid == 0) {
        float M = mred[0], S = sred[0];
        for (int i = 1; i < 4; i++) {
            const float nm = fmaxf(M, mred[i]);
            S = S * __expf(M - nm) + sred[i] * __expf(mred[i] - nm);
            M = nm;
        }
        rnll[row] = (M + logf(S)) - lr[targets[row]];
    }
}

__global__ __launch_bounds__(256) void k_loss_final(const float* __restrict__ rnll,
                                                    float* __restrict__ loss) {
    const int tid = threadIdx.x;
    float s = 0.f;
    for (int i = tid; i < BT; i += 256) s += rnll[i];
#pragma unroll
    for (int off = 32; off; off >>= 1) s += __shfl_xor(s, off);
    __shared__ float red[4];
    if ((tid & 63) == 0) red[tid >> 6] = s;
    __syncthreads();
    if (tid == 0) loss[0] = (red[0] + red[1] + red[2] + red[3]) / (float)BT;
}

// ---------------------------------------------------------------- launch
extern "C" void kernel_launch(void* const* d_in, const int* in_sizes, int n_in,
                              void* d_out, int out_size, void* d_ws, size_t ws_size,
                              hipStream_t stream) {
    const int*   idx     = (const int*)d_in[0];
    const int*   targets = (const int*)d_in[1];
    const float* wte     = (const float*)d_in[2];
    const float* wpe     = (const float*)d_in[3];
    const float* qkv_w   = (const float*)d_in[4];
    const float* proj_w  = (const float*)d_in[5];
    const float* proj_b  = (const float*)d_in[6];
    const float* ln1_g   = (const float*)d_in[7];
    const float* ln1_b   = (const float*)d_in[8];
    const float* ln2_g   = (const float*)d_in[9];
    const float* ln2_b   = (const float*)d_in[10];
    const float* fc1_w   = (const float*)d_in[11];
    const float* fc1_b   = (const float*)d_in[12];
    const float* fc2_w   = (const float*)d_in[13];
    const float* fc2_b   = (const float*)d_in[14];
    const float* lnf_g   = (const float*)d_in[15];
    const float* lnf_b   = (const float*)d_in[16];

    float* logits = (float*)d_out;
    float* loss   = logits + (size_t)BT * Vv;

    float* x     = (float*)d_ws;
    float* rnll  = x + (size_t)BT * Ee;
    short* qkvb  = (short*)(rnll + BT);
    short* h     = qkvb + (size_t)BT * 3 * Ee;
    short* y     = h  + (size_t)BT * Ee;
    short* h1    = y  + (size_t)BT * Ee;
    short* wT    = h1 + (size_t)BT * FFf;
    const size_t need = ((size_t)BT * Ee + BT) * sizeof(float)
                      + ((size_t)BT * (5 * Ee + FFf) + (size_t)FFf * Ee) * sizeof(short);
    if (ws_size < need) return;

    k_embed<<<BT, 256, 0, stream>>>(idx, wte, wpe, x);
    for (int l = 0; l < Ll; l++) {
        k_ln<<<BT, 256, 0, stream>>>(x, ln1_g + (size_t)l * Ee, ln1_b + (size_t)l * Ee, h);
        k_wT<<<dim3(3 * Ee / 32, Ee / 32), 256, 0, stream>>>(
            qkv_w + (size_t)l * Ee * 3 * Ee, wT, Ee, 3 * Ee);
        k_gemm<0, 0, short><<<dim3(BT / 128, 3 * Ee / 128), 256, 0, stream>>>(
            h, wT, nullptr, nullptr, qkvb, BT, 3 * Ee, Ee);
        k_attn<<<dim3(Tt / 64, Hh, Bb), 256, 0, stream>>>(qkvb, y);
        k_wT<<<dim3(Ee / 32, Ee / 32), 256, 0, stream>>>(
            proj_w + (size_t)l * Ee * Ee, wT, Ee, Ee);
        k_gemm<0, 3, float><<<dim3(BT / 128, Ee / 128), 256, 0, stream>>>(
            y, wT, proj_b + (size_t)l * Ee, x, x, BT, Ee, Ee);
        k_ln<<<BT, 256, 0, stream>>>(x, ln2_g + (size_t)l * Ee, ln2_b + (size_t)l * Ee, h);
        k_wT<<<dim3(FFf / 32, Ee / 32), 256, 0, stream>>>(
            fc1_w + (size_t)l * Ee * FFf, wT, Ee, FFf);
        k_gemm<0, 2, short><<<dim3(BT / 128, FFf / 128), 256, 0, stream>>>(
            h, wT, fc1_b + (size_t)l * FFf, nullptr, h1, BT, FFf, Ee);
        k_wT<<<dim3(Ee / 32, FFf / 32), 256, 0, stream>>>(
            fc2_w + (size_t)l * FFf * Ee, wT, FFf, Ee);
        k_gemm<0, 3, float><<<dim3(BT / 128, Ee / 128), 256, 0, stream>>>(
            h1, wT, fc2_b + (size_t)l * Ee, x, x, BT, Ee, FFf);
    }
    k_ln<<<BT, 256, 0, stream>>>(x, lnf_g, lnf_b, h);
    k_gemm<1, 0, float><<<dim3(BT / 128, (Vv + 127) / 128), 256, 0, stream>>>(
        h, wte, nullptr, nullptr, logits, BT, Vv, Ee);
    k_loss_row<<<BT, 256, 0, stream>>>(logits, targets, rnll);
    k_loss_final<<<1, 256, 0, stream>>>(rnll, loss);
}

// Round 6
// 4257.119 us; speedup vs baseline: 11.8873x; 1.0295x over previous
//
#include <hip/hip_runtime.h>
#include <math.h>

// GPT-2-ish forward: V=50257 E=1024 H=16 L=8 B=2 T=2048 HD=64 FF=4096
constexpr int Vv = 50257;
constexpr int Ee = 1024;
constexpr int Hh = 16;
constexpr int Ll = 8;
constexpr int Bb = 2;
constexpr int Tt = 2048;
constexpr int HDh = 64;
constexpr int FFf = 4096;
constexpr int BT = Bb * Tt;   // 4096 token rows

typedef __attribute__((ext_vector_type(8))) short bf16x8;
typedef __attribute__((ext_vector_type(4))) float f32x4;

__device__ __forceinline__ short f2b(float f) {   // f32 -> bf16 RNE
    union { float f; unsigned u; } c; c.f = f;
    unsigned u = c.u + 0x7fffu + ((c.u >> 16) & 1u);
    return (short)(u >> 16);
}

// async 16B global->LDS (dest = wave-uniform base + lane*16)
__device__ __forceinline__ void g2l16(void* lds, const void* g) {
    __builtin_amdgcn_global_load_lds(
        (const __attribute__((address_space(1))) void*)g,
        (__attribute__((address_space(3))) void*)lds, 16, 0, 0);
}

__device__ __forceinline__ float gelu_exact(float v) {
    return 0.5f * v * (1.0f + erff(v * 0.70710678118654752f));
}

// ---------------------------------------------------------------- embedding
__global__ __launch_bounds__(256) void k_embed(const int* __restrict__ idx,
                                               const float* __restrict__ wte,
                                               const float* __restrict__ wpe,
                                               float* __restrict__ x) {
    const int row = blockIdx.x;
    const int t = row % Tt;
    const int tok = idx[row];
    const int c = threadIdx.x * 4;
    const float4 a = *(const float4*)(wte + (size_t)tok * Ee + c);
    const float4 b = *(const float4*)(wpe + (size_t)t * Ee + c);
    *(float4*)(x + (size_t)row * Ee + c) =
        make_float4(a.x + b.x, a.y + b.y, a.z + b.z, a.w + b.w);
}

// ------------------------------------------------- layernorm (f32 in, bf16 out)
__global__ __launch_bounds__(256) void k_ln(const float* __restrict__ x,
                                            const float* __restrict__ g,
                                            const float* __restrict__ b,
                                            short* __restrict__ out) {
    const int row = blockIdx.x;
    const int tid = threadIdx.x;
    const float4 v = *(const float4*)(x + (size_t)row * Ee + tid * 4);
    float s  = v.x + v.y + v.z + v.w;
    float ss = v.x * v.x + v.y * v.y + v.z * v.z + v.w * v.w;
#pragma unroll
    for (int off = 32; off; off >>= 1) {
        s  += __shfl_down(s, off);
        ss += __shfl_down(ss, off);
    }
    __shared__ float red[8];
    const int wid = tid >> 6, lane = tid & 63;
    if (lane == 0) { red[wid] = s; red[4 + wid] = ss; }
    __syncthreads();
    const float S  = red[0] + red[1] + red[2] + red[3];
    const float SS = red[4] + red[5] + red[6] + red[7];
    const float mean = S * (1.f / Ee);
    const float var  = SS * (1.f / Ee) - mean * mean;
    const float inv  = rsqrtf(var + 1e-5f);
    const float4 gg = *(const float4*)(g + tid * 4);
    const float4 bb = *(const float4*)(b + tid * 4);
    short4 o;
    o.x = f2b((v.x - mean) * inv * gg.x + bb.x);
    o.y = f2b((v.y - mean) * inv * gg.y + bb.y);
    o.z = f2b((v.z - mean) * inv * gg.z + bb.z);
    o.w = f2b((v.w - mean) * inv * gg.w + bb.w);
    *(short4*)(out + (size_t)row * Ee + tid * 4) = o;
}

// ---------------------------- weight transpose+convert: w[K][N] f32 -> o[N][K] bf16
__global__ __launch_bounds__(256) void k_wT(const float* __restrict__ w,
                                            short* __restrict__ o, int K, int N) {
    __shared__ short t[32][33];
    const int n0 = blockIdx.x * 32, k0 = blockIdx.y * 32;
    const int tid = threadIdx.x;
    {
        const int k = tid >> 3, n4 = (tid & 7) * 4;
        const float4 v = *(const float4*)(w + (size_t)(k0 + k) * N + n0 + n4);
        t[n4 + 0][k] = f2b(v.x); t[n4 + 1][k] = f2b(v.y);
        t[n4 + 2][k] = f2b(v.z); t[n4 + 3][k] = f2b(v.w);
    }
    __syncthreads();
    {
        const int n = tid >> 3, k4 = (tid & 7) * 4;
        short4 s;
        s.x = t[n][k4]; s.y = t[n][k4 + 1]; s.z = t[n][k4 + 2]; s.w = t[n][k4 + 3];
        *(short4*)(o + (size_t)(n0 + n) * K + k0 + k4) = s;
    }
}

// ---------------------------- plain convert: w f32 -> bf16 (same layout), 8/thread
__global__ __launch_bounds__(256) void k_cvt(const float* __restrict__ w,
                                             short* __restrict__ o, int n8) {
    const int i = blockIdx.x * 256 + threadIdx.x;
    if (i >= n8) return;
    const float4 a = ((const float4*)w)[i * 2];
    const float4 b = ((const float4*)w)[i * 2 + 1];
    bf16x8 v = {f2b(a.x), f2b(a.y), f2b(a.z), f2b(a.w),
                f2b(b.x), f2b(b.y), f2b(b.z), f2b(b.w)};
    ((bf16x8*)o)[i] = v;
}

// ---------------------------------------------------------------- MFMA GEMM
// C[M,N] = A[M,K](bf16) @ B[N][K](bf16) + epilogue.
// EPI: 0 none, 2 bias+GELU, 3 bias+residual.  OT: float or short(bf16).
// SWZ: bijective XCD-chunk remap of the linear block id (m204 formula).
__device__ __forceinline__ void st_c(float* C, size_t i, float v) { C[i] = v; }
__device__ __forceinline__ void st_c(short* C, size_t i, float v) { C[i] = f2b(v); }

template <int EPI, int SWZ, typename OT>
__global__ __launch_bounds__(256) void k_gemm(const short* __restrict__ A,
                                              const short* __restrict__ Bp,
                                              const float* __restrict__ bias,
                                              const float* __restrict__ res,
                                              OT* __restrict__ C,
                                              int M, int N, int K) {
    __shared__ short As[128 * 32];
    __shared__ short Bs[128 * 32];
    const int tid = threadIdx.x, w = tid >> 6, ln = tid & 63;
    int bx = blockIdx.x, by = blockIdx.y;
    if (SWZ) {
        const int nwg = gridDim.x * gridDim.y;
        const int orig = by * gridDim.x + bx;
        const int q = nwg >> 3, r = nwg & 7;
        const int xcd = orig & 7, local = orig >> 3;
        const int wgid = (xcd < r ? xcd * (q + 1) : r * (q + 1) + (xcd - r) * q) + local;
        bx = wgid % gridDim.x;
        by = wgid / gridDim.x;
    }
    const int m0 = bx * 128, n0 = by * 128;
    const int wr = w >> 1, wc = w & 1;

    f32x4 zero = {0.f, 0.f, 0.f, 0.f};
    f32x4 acc[4][4];
#pragma unroll
    for (int i = 0; i < 4; i++)
#pragma unroll
        for (int j = 0; j < 4; j++) acc[i][j] = zero;

    const int srow = w * 32 + (ln >> 2);     // staging row within tile (wave part)
    const int scol = (ln & 3) * 8;           // staging k offset (8 bf16 = 16B)
    const int br0 = min(n0 + srow, N - 1);        // clamp for N-tail (logits)
    const int br1 = min(n0 + srow + 16, N - 1);

    for (int k0 = 0; k0 < K; k0 += 32) {
        __syncthreads();
        g2l16(&As[(w * 32 + 0) * 32],  A + (size_t)(m0 + srow) * K + k0 + scol);
        g2l16(&As[(w * 32 + 16) * 32], A + (size_t)(m0 + srow + 16) * K + k0 + scol);
        g2l16(&Bs[(w * 32 + 0) * 32],  Bp + (size_t)br0 * K + k0 + scol);
        g2l16(&Bs[(w * 32 + 16) * 32], Bp + (size_t)br1 * K + k0 + scol);
        __syncthreads();   // drains vmcnt (incl. global_load_lds) + lgkm
        bf16x8 af[4], bfv[4];
#pragma unroll
        for (int i = 0; i < 4; i++) {
            af[i]  = *(bf16x8*)&As[(wr * 64 + i * 16 + (ln & 15)) * 32 + (ln >> 4) * 8];
            bfv[i] = *(bf16x8*)&Bs[(wc * 64 + i * 16 + (ln & 15)) * 32 + (ln >> 4) * 8];
        }
#pragma unroll
        for (int i = 0; i < 4; i++)
#pragma unroll
            for (int j = 0; j < 4; j++)
                acc[i][j] = __builtin_amdgcn_mfma_f32_16x16x32_bf16(
                    af[i], bfv[j], acc[i][j], 0, 0, 0);
    }

    // --- epilogue: C/D layout col=lane&15, row=(lane>>4)*4+reg  [m89]
#pragma unroll
    for (int j = 0; j < 4; j++) {
        const int gcol = n0 + wc * 64 + j * 16 + (ln & 15);
        if (gcol < N) {
            const float bv = (EPI >= 2) ? bias[gcol] : 0.f;
#pragma unroll
            for (int i = 0; i < 4; i++) {
#pragma unroll
                for (int r = 0; r < 4; r++) {
                    const int grow = m0 + wr * 64 + i * 16 + (ln >> 4) * 4 + r;
                    float v = acc[i][j][r] + bv;
                    if (EPI == 2) v = gelu_exact(v);
                    if (EPI == 3) v += res[(size_t)grow * N + gcol];
                    st_c(C, (size_t)grow * N + gcol, v);
                }
            }
        }
    }
}

// ---------------------------------------------------------------- attention
// MFMA flash attention. Block = (b, h, 64 q-rows); 4 waves x 16 q-rows.
__global__ __launch_bounds__(256) void k_attn(const short* __restrict__ qkv,
                                              short* __restrict__ y) {
    __shared__ short Kl[64][72];      // [key][d]
    __shared__ short Vt[64][72];      // [d][key]   (transposed V)
    __shared__ short Pl[4][16][72];   // per-wave P [q][key]
    const int tid = threadIdx.x, w = tid >> 6, ln = tid & 63;
    const int q0 = blockIdx.x * 64, h = blockIdx.y, b = blockIdx.z;
    const size_t base = ((size_t)b * Tt) * (3 * Ee) + h * HDh;

    bf16x8 qf[2];
    {
        const int qr = q0 + w * 16 + (ln & 15);
        const short* qp = qkv + base + (size_t)qr * (3 * Ee) + (ln >> 4) * 8;
        qf[0] = *(const bf16x8*)(qp);
        qf[1] = *(const bf16x8*)(qp + 32);
    }

    f32x4 zero = {0.f, 0.f, 0.f, 0.f};
    f32x4 oc[4];
#pragma unroll
    for (int i = 0; i < 4; i++) oc[i] = zero;
    float mx[4], ls[4];
#pragma unroll
    for (int r = 0; r < 4; r++) { mx[r] = -INFINITY; ls[r] = 0.f; }

    const int nt = blockIdx.x + 1;
    for (int j = 0; j < nt; j++) {
        const int kb = j * 64;
        __syncthreads();
        {
            const int r = tid >> 2, d0 = (tid & 3) * 16;
            const short* kp = qkv + base + Ee     + (size_t)(kb + r) * (3 * Ee) + d0;
            const short* vp = qkv + base + 2 * Ee + (size_t)(kb + r) * (3 * Ee) + d0;
            *(bf16x8*)&Kl[r][d0]     = *(const bf16x8*)(kp);
            *(bf16x8*)&Kl[r][d0 + 8] = *(const bf16x8*)(kp + 8);
            bf16x8 v0 = *(const bf16x8*)(vp);
            bf16x8 v1 = *(const bf16x8*)(vp + 8);
#pragma unroll
            for (int p = 0; p < 8; p++) Vt[d0 + p][r] = v0[p];
#pragma unroll
            for (int p = 0; p < 8; p++) Vt[d0 + 8 + p][r] = v1[p];
        }
        __syncthreads();

        f32x4 sc[4];
#pragma unroll
        for (int kcb = 0; kcb < 4; kcb++) {
            const int krow = kcb * 16 + (ln & 15);
            bf16x8 kf0 = *(bf16x8*)&Kl[krow][(ln >> 4) * 8];
            bf16x8 kf1 = *(bf16x8*)&Kl[krow][(ln >> 4) * 8 + 32];
            f32x4 s = __builtin_amdgcn_mfma_f32_16x16x32_bf16(qf[0], kf0, zero, 0, 0, 0);
            sc[kcb]  = __builtin_amdgcn_mfma_f32_16x16x32_bf16(qf[1], kf1, s, 0, 0, 0);
        }
        float pv[4][4];
        float tmv[4] = {-INFINITY, -INFINITY, -INFINITY, -INFINITY};
#pragma unroll
        for (int kcb = 0; kcb < 4; kcb++) {
            const int col = kb + kcb * 16 + (ln & 15);
#pragma unroll
            for (int r = 0; r < 4; r++) {
                const int qr = q0 + w * 16 + (ln >> 4) * 4 + r;
                const float sv = (col <= qr) ? sc[kcb][r] * 0.125f : -INFINITY;
                pv[kcb][r] = sv;
                tmv[r] = fmaxf(tmv[r], sv);
            }
        }
#pragma unroll
        for (int off = 1; off < 16; off <<= 1)
#pragma unroll
            for (int r = 0; r < 4; r++) tmv[r] = fmaxf(tmv[r], __shfl_xor(tmv[r], off));
        float rs[4];
#pragma unroll
        for (int r = 0; r < 4; r++) {
            const float nm = fmaxf(mx[r], tmv[r]);
            const float alpha = __expf(mx[r] - nm);
            mx[r] = nm;
            float acc_s = 0.f;
#pragma unroll
            for (int kcb = 0; kcb < 4; kcb++) {
                const float e = __expf(pv[kcb][r] - nm);
                pv[kcb][r] = e;
                acc_s += e;
            }
            rs[r] = acc_s;
            ls[r] *= alpha;
#pragma unroll
            for (int db = 0; db < 4; db++) oc[db][r] *= alpha;
        }
#pragma unroll
        for (int off = 1; off < 16; off <<= 1)
#pragma unroll
            for (int r = 0; r < 4; r++) rs[r] += __shfl_xor(rs[r], off);
#pragma unroll
        for (int r = 0; r < 4; r++) ls[r] += rs[r];
#pragma unroll
        for (int kcb = 0; kcb < 4; kcb++)
#pragma unroll
            for (int r = 0; r < 4; r++)
                Pl[w][(ln >> 4) * 4 + r][kcb * 16 + (ln & 15)] = f2b(pv[kcb][r]);
        bf16x8 pf0 = *(bf16x8*)&Pl[w][ln & 15][(ln >> 4) * 8];
        bf16x8 pf1 = *(bf16x8*)&Pl[w][ln & 15][(ln >> 4) * 8 + 32];
#pragma unroll
        for (int db = 0; db < 4; db++) {
            const int drow = db * 16 + (ln & 15);
            bf16x8 vf0 = *(bf16x8*)&Vt[drow][(ln >> 4) * 8];
            bf16x8 vf1 = *(bf16x8*)&Vt[drow][(ln >> 4) * 8 + 32];
            oc[db] = __builtin_amdgcn_mfma_f32_16x16x32_bf16(pf0, vf0, oc[db], 0, 0, 0);
            oc[db] = __builtin_amdgcn_mfma_f32_16x16x32_bf16(pf1, vf1, oc[db], 0, 0, 0);
        }
    }
#pragma unroll
    for (int r = 0; r < 4; r++) {
        const int qr = q0 + w * 16 + (ln >> 4) * 4 + r;
        const float inv = 1.f / ls[r];
#pragma unroll
        for (int db = 0; db < 4; db++)
            y[(size_t)(b * Tt + qr) * Ee + h * HDh + db * 16 + (ln & 15)] =
                f2b(oc[db][r] * inv);
    }
}

// ---------------------------------------------------------------- loss
__global__ __launch_bounds__(256) void k_loss_row(const float* __restrict__ logits,
                                                  const int* __restrict__ targets,
                                                  float* __restrict__ rnll) {
    const int row = blockIdx.x;
    const float* lr = logits + (size_t)row * Vv;
    const int tid = threadIdx.x;
    float m = -INFINITY, s = 0.f;
    // 49 full float4 passes (49*1024 = 50176 <= Vv), then 81-elem tail
#pragma unroll 4
    for (int k = 0; k < 49; k++) {
        const float4 v = *(const float4*)(lr + tid * 4 + k * 1024);
        const float m4 = fmaxf(fmaxf(v.x, v.y), fmaxf(v.z, v.w));
        const float nm = fmaxf(m, m4);
        s = s * __expf(m - nm) + __expf(v.x - nm) + __expf(v.y - nm)
            + __expf(v.z - nm) + __expf(v.w - nm);
        m = nm;
    }
    {
        const int i = 50176 + tid;
        if (i < Vv) {
            const float xv = lr[i];
            const float nm = fmaxf(m, xv);
            s = s * __expf(m - nm) + __expf(xv - nm);
            m = nm;
        }
    }
#pragma unroll
    for (int off = 32; off; off >>= 1) {
        const float m2 = __shfl_xor(m, off);
        const float s2 = __shfl_xor(s, off);
        const float nm = fmaxf(m, m2);
        s = s * __expf(m - nm) + s2 * __expf(m2 - nm);
        m = nm;
    }
    __shared__ float mred[4], sred[4];
    const int wid = tid >> 6, lane = tid & 63;
    if (lane == 0) { mred[wid] = m; sred[wid] = s; }
    __syncthreads();
    if (tid == 0) {
        float M = mred[0], S = sred[0];
        for (int i = 1; i < 4; i++) {
            const float nm = fmaxf(M, mred[i]);
            S = S * __expf(M - nm) + sred[i] * __expf(mred[i] - nm);
            M = nm;
        }
        rnll[row] = (M + logf(S)) - lr[targets[row]];
    }
}

__global__ __launch_bounds__(256) void k_loss_final(const float* __restrict__ rnll,
                                                    float* __restrict__ loss) {
    const int tid = threadIdx.x;
    float s = 0.f;
    for (int i = tid; i < BT; i += 256) s += rnll[i];
#pragma unroll
    for (int off = 32; off; off >>= 1) s += __shfl_xor(s, off);
    __shared__ float red[4];
    if ((tid & 63) == 0) red[tid >> 6] = s;
    __syncthreads();
    if (tid == 0) loss[0] = (red[0] + red[1] + red[2] + red[3]) / (float)BT;
}

// ---------------------------------------------------------------- launch
extern "C" void kernel_launch(void* const* d_in, const int* in_sizes, int n_in,
                              void* d_out, int out_size, void* d_ws, size_t ws_size,
                              hipStream_t stream) {
    const int*   idx     = (const int*)d_in[0];
    const int*   targets = (const int*)d_in[1];
    const float* wte     = (const float*)d_in[2];
    const float* wpe     = (const float*)d_in[3];
    const float* qkv_w   = (const float*)d_in[4];
    const float* proj_w  = (const float*)d_in[5];
    const float* proj_b  = (const float*)d_in[6];
    const float* ln1_g   = (const float*)d_in[7];
    const float* ln1_b   = (const float*)d_in[8];
    const float* ln2_g   = (const float*)d_in[9];
    const float* ln2_b   = (const float*)d_in[10];
    const float* fc1_w   = (const float*)d_in[11];
    const float* fc1_b   = (const float*)d_in[12];
    const float* fc2_w   = (const float*)d_in[13];
    const float* fc2_b   = (const float*)d_in[14];
    const float* lnf_g   = (const float*)d_in[15];
    const float* lnf_b   = (const float*)d_in[16];

    float* logits = (float*)d_out;
    float* loss   = logits + (size_t)BT * Vv;

    // Workspace: layer-phase buffers (x,qkvb,y,h1,wT ~92 MB) are overlaid by
    // wteb (bf16 wte, 103 MB) which is written only AFTER the final k_ln has
    // consumed x. h + rnll live above the overlay region.
    short* wteb = (short*)d_ws;                         // [V][E] bf16 (late)
    float* x    = (float*)d_ws;                         // overlay (dead by cvt)
    short* qkvb = (short*)(x + (size_t)BT * Ee);
    short* y    = qkvb + (size_t)BT * 3 * Ee;
    short* h1   = y + (size_t)BT * Ee;
    short* wT   = h1 + (size_t)BT * FFf;
    const size_t OFF = (size_t)Vv * Ee * 2;             // 102.9 MB, 256B-aligned
    short* h    = (short*)((char*)d_ws + OFF);
    float* rnll = (float*)(h + (size_t)BT * Ee);
    const size_t need = OFF + (size_t)BT * Ee * 2 + BT * sizeof(float);
    if (ws_size < need) return;

    k_embed<<<BT, 256, 0, stream>>>(idx, wte, wpe, x);
    for (int l = 0; l < Ll; l++) {
        k_ln<<<BT, 256, 0, stream>>>(x, ln1_g + (size_t)l * Ee, ln1_b + (size_t)l * Ee, h);
        k_wT<<<dim3(3 * Ee / 32, Ee / 32), 256, 0, stream>>>(
            qkv_w + (size_t)l * Ee * 3 * Ee, wT, Ee, 3 * Ee);
        k_gemm<0, 1, short><<<dim3(BT / 128, 3 * Ee / 128), 256, 0, stream>>>(
            h, wT, nullptr, nullptr, qkvb, BT, 3 * Ee, Ee);
        k_attn<<<dim3(Tt / 64, Hh, Bb), 256, 0, stream>>>(qkvb, y);
        k_wT<<<dim3(Ee / 32, Ee / 32), 256, 0, stream>>>(
            proj_w + (size_t)l * Ee * Ee, wT, Ee, Ee);
        k_gemm<3, 1, float><<<dim3(BT / 128, Ee / 128), 256, 0, stream>>>(
            y, wT, proj_b + (size_t)l * Ee, x, x, BT, Ee, Ee);
        k_ln<<<BT, 256, 0, stream>>>(x, ln2_g + (size_t)l * Ee, ln2_b + (size_t)l * Ee, h);
        k_wT<<<dim3(FFf / 32, Ee / 32), 256, 0, stream>>>(
            fc1_w + (size_t)l * Ee * FFf, wT, Ee, FFf);
        k_gemm<2, 1, short><<<dim3(BT / 128, FFf / 128), 256, 0, stream>>>(
            h, wT, fc1_b + (size_t)l * FFf, nullptr, h1, BT, FFf, Ee);
        k_wT<<<dim3(Ee / 32, FFf / 32), 256, 0, stream>>>(
            fc2_w + (size_t)l * FFf * Ee, wT, FFf, Ee);
        k_gemm<3, 1, float><<<dim3(BT / 128, Ee / 128), 256, 0, stream>>>(
            h1, wT, fc2_b + (size_t)l * Ee, x, x, BT, Ee, FFf);
    }
    k_ln<<<BT, 256, 0, stream>>>(x, lnf_g, lnf_b, h);
    // x (and all other overlay buffers) now dead -> write wteb over them
    k_cvt<<<(Vv * Ee / 8 + 255) / 256, 256, 0, stream>>>(wte, wteb, Vv * Ee / 8);
    k_gemm<0, 1, float><<<dim3(BT / 128, (Vv + 127) / 128), 256, 0, stream>>>(
        h, wteb, nullptr, nullptr, logits, BT, Vv, Ee);
    k_loss_row<<<BT, 256, 0, stream>>>(logits, targets, rnll);
    k_loss_final<<<1, 256, 0, stream>>>(rnll, loss);
}

// Round 7
// 4112.983 us; speedup vs baseline: 12.3039x; 1.0350x over previous
//
#include <hip/hip_runtime.h>
#include <math.h>

// GPT-2-ish forward: V=50257 E=1024 H=16 L=8 B=2 T=2048 HD=64 FF=4096
constexpr int Vv = 50257;
constexpr int Ee = 1024;
constexpr int Hh = 16;
constexpr int Ll = 8;
constexpr int Bb = 2;
constexpr int Tt = 2048;
constexpr int HDh = 64;
constexpr int FFf = 4096;
constexpr int BT = Bb * Tt;   // 4096 token rows

typedef __attribute__((ext_vector_type(8))) short bf16x8;
typedef __attribute__((ext_vector_type(4))) float f32x4;

__device__ __forceinline__ short f2b(float f) {   // f32 -> bf16 RNE
    union { float f; unsigned u; } c; c.f = f;
    unsigned u = c.u + 0x7fffu + ((c.u >> 16) & 1u);
    return (short)(u >> 16);
}

// async 16B global->LDS (dest = wave-uniform base + lane*16)
__device__ __forceinline__ void g2l16(void* lds, const void* g) {
    __builtin_amdgcn_global_load_lds(
        (const __attribute__((address_space(1))) void*)g,
        (__attribute__((address_space(3))) void*)lds, 16, 0, 0);
}

__device__ __forceinline__ float gelu_exact(float v) {
    return 0.5f * v * (1.0f + erff(v * 0.70710678118654752f));
}

// ---------------------------------------------------------------- embedding
__global__ __launch_bounds__(256) void k_embed(const int* __restrict__ idx,
                                               const float* __restrict__ wte,
                                               const float* __restrict__ wpe,
                                               float* __restrict__ x) {
    const int row = blockIdx.x;
    const int t = row % Tt;
    const int tok = idx[row];
    const int c = threadIdx.x * 4;
    const float4 a = *(const float4*)(wte + (size_t)tok * Ee + c);
    const float4 b = *(const float4*)(wpe + (size_t)t * Ee + c);
    *(float4*)(x + (size_t)row * Ee + c) =
        make_float4(a.x + b.x, a.y + b.y, a.z + b.z, a.w + b.w);
}

// ------------------------------------------------- layernorm (f32 in, bf16 out)
__global__ __launch_bounds__(256) void k_ln(const float* __restrict__ x,
                                            const float* __restrict__ g,
                                            const float* __restrict__ b,
                                            short* __restrict__ out) {
    const int row = blockIdx.x;
    const int tid = threadIdx.x;
    const float4 v = *(const float4*)(x + (size_t)row * Ee + tid * 4);
    float s  = v.x + v.y + v.z + v.w;
    float ss = v.x * v.x + v.y * v.y + v.z * v.z + v.w * v.w;
#pragma unroll
    for (int off = 32; off; off >>= 1) {
        s  += __shfl_down(s, off);
        ss += __shfl_down(ss, off);
    }
    __shared__ float red[8];
    const int wid = tid >> 6, lane = tid & 63;
    if (lane == 0) { red[wid] = s; red[4 + wid] = ss; }
    __syncthreads();
    const float S  = red[0] + red[1] + red[2] + red[3];
    const float SS = red[4] + red[5] + red[6] + red[7];
    const float mean = S * (1.f / Ee);
    const float var  = SS * (1.f / Ee) - mean * mean;
    const float inv  = rsqrtf(var + 1e-5f);
    const float4 gg = *(const float4*)(g + tid * 4);
    const float4 bb = *(const float4*)(b + tid * 4);
    short4 o;
    o.x = f2b((v.x - mean) * inv * gg.x + bb.x);
    o.y = f2b((v.y - mean) * inv * gg.y + bb.y);
    o.z = f2b((v.z - mean) * inv * gg.z + bb.z);
    o.w = f2b((v.w - mean) * inv * gg.w + bb.w);
    *(short4*)(out + (size_t)row * Ee + tid * 4) = o;
}

// ---------------------------- weight transpose+convert: w[K][N] f32 -> o[N][K] bf16
__global__ __launch_bounds__(256) void k_wT(const float* __restrict__ w,
                                            short* __restrict__ o, int K, int N) {
    __shared__ short t[32][33];
    const int n0 = blockIdx.x * 32, k0 = blockIdx.y * 32;
    const int tid = threadIdx.x;
    {
        const int k = tid >> 3, n4 = (tid & 7) * 4;
        const float4 v = *(const float4*)(w + (size_t)(k0 + k) * N + n0 + n4);
        t[n4 + 0][k] = f2b(v.x); t[n4 + 1][k] = f2b(v.y);
        t[n4 + 2][k] = f2b(v.z); t[n4 + 3][k] = f2b(v.w);
    }
    __syncthreads();
    {
        const int n = tid >> 3, k4 = (tid & 7) * 4;
        short4 s;
        s.x = t[n][k4]; s.y = t[n][k4 + 1]; s.z = t[n][k4 + 2]; s.w = t[n][k4 + 3];
        *(short4*)(o + (size_t)(n0 + n) * K + k0 + k4) = s;
    }
}

// ---------------------------- plain convert: w f32 -> bf16 (same layout), 8/thread
__global__ __launch_bounds__(256) void k_cvt(const float* __restrict__ w,
                                             short* __restrict__ o, int n8) {
    const int i = blockIdx.x * 256 + threadIdx.x;
    if (i >= n8) return;
    const float4 a = ((const float4*)w)[i * 2];
    const float4 b = ((const float4*)w)[i * 2 + 1];
    bf16x8 v = {f2b(a.x), f2b(a.y), f2b(a.z), f2b(a.w),
                f2b(b.x), f2b(b.y), f2b(b.z), f2b(b.w)};
    ((bf16x8*)o)[i] = v;
}

// ---------------------------------------------------------------- MFMA GEMM
// C[M,N] = A[M,K](bf16) @ B[N][K](bf16) + epilogue.
// EPI: 0 none, 2 bias+GELU, 3 bias+residual, 4 none + LSE partials (pmax/psum).
// SWZ: bijective XCD-chunk remap. BN64f: 1 -> 64-wide N tile (2x blocks).
__device__ __forceinline__ void st_c(float* C, size_t i, float v) { C[i] = v; }
__device__ __forceinline__ void st_c(short* C, size_t i, float v) { C[i] = f2b(v); }

template <int EPI, int SWZ, int BN64f, typename OT>
__global__ __launch_bounds__(256) void k_gemm(const short* __restrict__ A,
                                              const short* __restrict__ Bp,
                                              const float* __restrict__ bias,
                                              const float* __restrict__ res,
                                              OT* __restrict__ C,
                                              int M, int N, int K,
                                              float* __restrict__ pmax,
                                              float* __restrict__ psum, int nt2) {
    constexpr int BN = BN64f ? 64 : 128;
    constexpr int NJ = BN64f ? 2 : 4;       // n-frags per wave
    constexpr int WCOL = BN64f ? 32 : 64;   // per-wave col extent
    __shared__ short As[128 * 32];
    __shared__ short Bs[BN * 32];
    const int tid = threadIdx.x, w = tid >> 6, ln = tid & 63;
    int bx = blockIdx.x, by = blockIdx.y;
    if (SWZ) {
        const int nwg = gridDim.x * gridDim.y;
        const int orig = by * gridDim.x + bx;
        const int q = nwg >> 3, r = nwg & 7;
        const int xcd = orig & 7, local = orig >> 3;
        const int wgid = (xcd < r ? xcd * (q + 1) : r * (q + 1) + (xcd - r) * q) + local;
        bx = wgid % gridDim.x;
        by = wgid / gridDim.x;
    }
    const int m0 = bx * 128, n0 = by * BN;
    const int wr = w >> 1, wc = w & 1;

    f32x4 zero = {0.f, 0.f, 0.f, 0.f};
    f32x4 acc[4][NJ];
#pragma unroll
    for (int i = 0; i < 4; i++)
#pragma unroll
        for (int j = 0; j < NJ; j++) acc[i][j] = zero;

    const int srow = w * 32 + (ln >> 2);     // A staging row (128 rows over 256 thr x2)
    const int scol = (ln & 3) * 8;           // staging k offset (8 bf16 = 16B)
    const int sb   = tid >> 2;               // B staging row for BN64 (64 rows)
    const int br0 = min(n0 + srow, N - 1);   // clamps for N-tail (logits)
    const int br1 = min(n0 + srow + 16, N - 1);
    const int brs = min(n0 + sb, N - 1);

    for (int k0 = 0; k0 < K; k0 += 32) {
        __syncthreads();
        g2l16(&As[(w * 32 + 0) * 32],  A + (size_t)(m0 + srow) * K + k0 + scol);
        g2l16(&As[(w * 32 + 16) * 32], A + (size_t)(m0 + srow + 16) * K + k0 + scol);
        if (BN64f) {
            g2l16(&Bs[sb * 32], Bp + (size_t)brs * K + k0 + scol);
        } else {
            g2l16(&Bs[(w * 32 + 0) * 32],  Bp + (size_t)br0 * K + k0 + scol);
            g2l16(&Bs[(w * 32 + 16) * 32], Bp + (size_t)br1 * K + k0 + scol);
        }
        __syncthreads();   // drains vmcnt (incl. global_load_lds) + lgkm
        bf16x8 af[4], bfv[NJ];
#pragma unroll
        for (int i = 0; i < 4; i++)
            af[i]  = *(bf16x8*)&As[(wr * 64 + i * 16 + (ln & 15)) * 32 + (ln >> 4) * 8];
#pragma unroll
        for (int j = 0; j < NJ; j++)
            bfv[j] = *(bf16x8*)&Bs[(wc * WCOL + j * 16 + (ln & 15)) * 32 + (ln >> 4) * 8];
#pragma unroll
        for (int i = 0; i < 4; i++)
#pragma unroll
            for (int j = 0; j < NJ; j++)
                acc[i][j] = __builtin_amdgcn_mfma_f32_16x16x32_bf16(
                    af[i], bfv[j], acc[i][j], 0, 0, 0);
    }

    // --- epilogue: C/D layout col=lane&15, row=(lane>>4)*4+reg  [m89]
#pragma unroll
    for (int j = 0; j < NJ; j++) {
        const int gcol = n0 + wc * WCOL + j * 16 + (ln & 15);
        if (gcol < N) {
            const float bv = (EPI == 2 || EPI == 3) ? bias[gcol] : 0.f;
#pragma unroll
            for (int i = 0; i < 4; i++) {
#pragma unroll
                for (int r = 0; r < 4; r++) {
                    const int grow = m0 + wr * 64 + i * 16 + (ln >> 4) * 4 + r;
                    float v = acc[i][j][r] + bv;
                    if (EPI == 2) v = gelu_exact(v);
                    if (EPI == 3) v += res[(size_t)grow * N + gcol];
                    st_c(C, (size_t)grow * N + gcol, v);
                }
            }
        }
    }
    if (EPI == 4) {   // per-(row, 64-col wave-half) LSE partials
#pragma unroll
        for (int i = 0; i < 4; i++) {
#pragma unroll
            for (int r = 0; r < 4; r++) {
                const int grow = m0 + wr * 64 + i * 16 + (ln >> 4) * 4 + r;
                float vv[NJ], pm = -INFINITY;
#pragma unroll
                for (int j = 0; j < NJ; j++) {
                    const int gcol = n0 + wc * WCOL + j * 16 + (ln & 15);
                    vv[j] = (gcol < N) ? acc[i][j][r] : -INFINITY;
                    pm = fmaxf(pm, vv[j]);
                }
#pragma unroll
                for (int off = 1; off < 16; off <<= 1) pm = fmaxf(pm, __shfl_xor(pm, off));
                float ps = 0.f;
#pragma unroll
                for (int j = 0; j < NJ; j++)
                    ps += (vv[j] > -INFINITY) ? __expf(vv[j] - pm) : 0.f;
#pragma unroll
                for (int off = 1; off < 16; off <<= 1) ps += __shfl_xor(ps, off);
                if ((ln & 15) == 0) {
                    pmax[(size_t)grow * nt2 + by * 2 + wc] = pm;
                    psum[(size_t)grow * nt2 + by * 2 + wc] = ps;
                }
            }
        }
    }
}

// ---------------------------------------------------------------- attention
// MFMA flash attention. Block = (b, h, 64 q-rows); 4 waves x 16 q-rows.
__global__ __launch_bounds__(256) void k_attn(const short* __restrict__ qkv,
                                              short* __restrict__ y) {
    __shared__ short Kl[64][72];      // [key][d]
    __shared__ short Vt[64][72];      // [d][key]   (transposed V)
    __shared__ short Pl[4][16][72];   // per-wave P [q][key]
    const int tid = threadIdx.x, w = tid >> 6, ln = tid & 63;
    const int q0 = blockIdx.x * 64, h = blockIdx.y, b = blockIdx.z;
    const size_t base = ((size_t)b * Tt) * (3 * Ee) + h * HDh;

    bf16x8 qf[2];
    {
        const int qr = q0 + w * 16 + (ln & 15);
        const short* qp = qkv + base + (size_t)qr * (3 * Ee) + (ln >> 4) * 8;
        qf[0] = *(const bf16x8*)(qp);
        qf[1] = *(const bf16x8*)(qp + 32);
    }

    f32x4 zero = {0.f, 0.f, 0.f, 0.f};
    f32x4 oc[4];
#pragma unroll
    for (int i = 0; i < 4; i++) oc[i] = zero;
    float mx[4], ls[4];
#pragma unroll
    for (int r = 0; r < 4; r++) { mx[r] = -INFINITY; ls[r] = 0.f; }

    const int nt = blockIdx.x + 1;
    for (int j = 0; j < nt; j++) {
        const int kb = j * 64;
        __syncthreads();
        {
            const int r = tid >> 2, d0 = (tid & 3) * 16;
            const short* kp = qkv + base + Ee     + (size_t)(kb + r) * (3 * Ee) + d0;
            const short* vp = qkv + base + 2 * Ee + (size_t)(kb + r) * (3 * Ee) + d0;
            *(bf16x8*)&Kl[r][d0]     = *(const bf16x8*)(kp);
            *(bf16x8*)&Kl[r][d0 + 8] = *(const bf16x8*)(kp + 8);
            bf16x8 v0 = *(const bf16x8*)(vp);
            bf16x8 v1 = *(const bf16x8*)(vp + 8);
#pragma unroll
            for (int p = 0; p < 8; p++) Vt[d0 + p][r] = v0[p];
#pragma unroll
            for (int p = 0; p < 8; p++) Vt[d0 + 8 + p][r] = v1[p];
        }
        __syncthreads();

        f32x4 sc[4];
#pragma unroll
        for (int kcb = 0; kcb < 4; kcb++) {
            const int krow = kcb * 16 + (ln & 15);
            bf16x8 kf0 = *(bf16x8*)&Kl[krow][(ln >> 4) * 8];
            bf16x8 kf1 = *(bf16x8*)&Kl[krow][(ln >> 4) * 8 + 32];
            f32x4 s = __builtin_amdgcn_mfma_f32_16x16x32_bf16(qf[0], kf0, zero, 0, 0, 0);
            sc[kcb]  = __builtin_amdgcn_mfma_f32_16x16x32_bf16(qf[1], kf1, s, 0, 0, 0);
        }
        float pv[4][4];
        float tmv[4] = {-INFINITY, -INFINITY, -INFINITY, -INFINITY};
#pragma unroll
        for (int kcb = 0; kcb < 4; kcb++) {
            const int col = kb + kcb * 16 + (ln & 15);
#pragma unroll
            for (int r = 0; r < 4; r++) {
                const int qr = q0 + w * 16 + (ln >> 4) * 4 + r;
                const float sv = (col <= qr) ? sc[kcb][r] * 0.125f : -INFINITY;
                pv[kcb][r] = sv;
                tmv[r] = fmaxf(tmv[r], sv);
            }
        }
#pragma unroll
        for (int off = 1; off < 16; off <<= 1)
#pragma unroll
            for (int r = 0; r < 4; r++) tmv[r] = fmaxf(tmv[r], __shfl_xor(tmv[r], off));
        float rs[4];
#pragma unroll
        for (int r = 0; r < 4; r++) {
            const float nm = fmaxf(mx[r], tmv[r]);
            const float alpha = __expf(mx[r] - nm);
            mx[r] = nm;
            float acc_s = 0.f;
#pragma unroll
            for (int kcb = 0; kcb < 4; kcb++) {
                const float e = __expf(pv[kcb][r] - nm);
                pv[kcb][r] = e;
                acc_s += e;
            }
            rs[r] = acc_s;
            ls[r] *= alpha;
#pragma unroll
            for (int db = 0; db < 4; db++) oc[db][r] *= alpha;
        }
#pragma unroll
        for (int off = 1; off < 16; off <<= 1)
#pragma unroll
            for (int r = 0; r < 4; r++) rs[r] += __shfl_xor(rs[r], off);
#pragma unroll
        for (int r = 0; r < 4; r++) ls[r] += rs[r];
#pragma unroll
        for (int kcb = 0; kcb < 4; kcb++)
#pragma unroll
            for (int r = 0; r < 4; r++)
                Pl[w][(ln >> 4) * 4 + r][kcb * 16 + (ln & 15)] = f2b(pv[kcb][r]);
        bf16x8 pf0 = *(bf16x8*)&Pl[w][ln & 15][(ln >> 4) * 8];
        bf16x8 pf1 = *(bf16x8*)&Pl[w][ln & 15][(ln >> 4) * 8 + 32];
#pragma unroll
        for (int db = 0; db < 4; db++) {
            const int drow = db * 16 + (ln & 15);
            bf16x8 vf0 = *(bf16x8*)&Vt[drow][(ln >> 4) * 8];
            bf16x8 vf1 = *(bf16x8*)&Vt[drow][(ln >> 4) * 8 + 32];
            oc[db] = __builtin_amdgcn_mfma_f32_16x16x32_bf16(pf0, vf0, oc[db], 0, 0, 0);
            oc[db] = __builtin_amdgcn_mfma_f32_16x16x32_bf16(pf1, vf1, oc[db], 0, 0, 0);
        }
    }
#pragma unroll
    for (int r = 0; r < 4; r++) {
        const int qr = q0 + w * 16 + (ln >> 4) * 4 + r;
        const float inv = 1.f / ls[r];
#pragma unroll
        for (int db = 0; db < 4; db++)
            y[(size_t)(b * Tt + qr) * Ee + h * HDh + db * 16 + (ln & 15)] =
                f2b(oc[db][r] * inv);
    }
}

// ---------------------------------------------------------------- loss
// finalize LSE from per-block partials; one wave per row
__global__ __launch_bounds__(256) void k_loss_fin(const float* __restrict__ pmax,
                                                  const float* __restrict__ psum,
                                                  const float* __restrict__ logits,
                                                  const int* __restrict__ targets,
                                                  float* __restrict__ rnll, int nt2) {
    const int row = blockIdx.x * 4 + (threadIdx.x >> 6);
    const int ln = threadIdx.x & 63;
    const float* pm = pmax + (size_t)row * nt2;
    const float* ps = psum + (size_t)row * nt2;
    float M = -INFINITY;
    for (int i = ln; i < nt2; i += 64) M = fmaxf(M, pm[i]);
#pragma unroll
    for (int off = 32; off; off >>= 1) M = fmaxf(M, __shfl_xor(M, off));
    float S = 0.f;
    for (int i = ln; i < nt2; i += 64) S += ps[i] * __expf(pm[i] - M);
#pragma unroll
    for (int off = 32; off; off >>= 1) S += __shfl_xor(S, off);
    if (ln == 0)
        rnll[row] = (M + logf(S)) - logits[(size_t)row * Vv + targets[row]];
}

__global__ __launch_bounds__(256) void k_loss_final(const float* __restrict__ rnll,
                                                    float* __restrict__ loss) {
    const int tid = threadIdx.x;
    float s = 0.f;
    for (int i = tid; i < BT; i += 256) s += rnll[i];
#pragma unroll
    for (int off = 32; off; off >>= 1) s += __shfl_xor(s, off);
    __shared__ float red[4];
    if ((tid & 63) == 0) red[tid >> 6] = s;
    __syncthreads();
    if (tid == 0) loss[0] = (red[0] + red[1] + red[2] + red[3]) / (float)BT;
}

// ---------------------------------------------------------------- launch
extern "C" void kernel_launch(void* const* d_in, const int* in_sizes, int n_in,
                              void* d_out, int out_size, void* d_ws, size_t ws_size,
                              hipStream_t stream) {
    const int*   idx     = (const int*)d_in[0];
    const int*   targets = (const int*)d_in[1];
    const float* wte     = (const float*)d_in[2];
    const float* wpe     = (const float*)d_in[3];
    const float* qkv_w   = (const float*)d_in[4];
    const float* proj_w  = (const float*)d_in[5];
    const float* proj_b  = (const float*)d_in[6];
    const float* ln1_g   = (const float*)d_in[7];
    const float* ln1_b   = (const float*)d_in[8];
    const float* ln2_g   = (const float*)d_in[9];
    const float* ln2_b   = (const float*)d_in[10];
    const float* fc1_w   = (const float*)d_in[11];
    const float* fc1_b   = (const float*)d_in[12];
    const float* fc2_w   = (const float*)d_in[13];
    const float* fc2_b   = (const float*)d_in[14];
    const float* lnf_g   = (const float*)d_in[15];
    const float* lnf_b   = (const float*)d_in[16];

    float* logits = (float*)d_out;
    float* loss   = logits + (size_t)BT * Vv;

    constexpr int NT2 = 2 * ((Vv + 127) / 128);        // 786 LSE partial slots/row

    // Workspace: layer-phase buffers (x,qkvb,y,h1,wT ~92 MB) overlaid by
    // wteb (bf16 wte, 103 MB) written only AFTER the final k_ln consumed x.
    short* wteb = (short*)d_ws;                         // [V][E] bf16 (late)
    float* x    = (float*)d_ws;                         // overlay (dead by cvt)
    short* qkvb = (short*)(x + (size_t)BT * Ee);
    short* y    = qkvb + (size_t)BT * 3 * Ee;
    short* h1   = y + (size_t)BT * Ee;
    short* wT   = h1 + (size_t)BT * FFf;
    const size_t OFF = (size_t)Vv * Ee * 2;             // 102.9 MB
    short* h    = (short*)((char*)d_ws + OFF);
    float* rnll = (float*)(h + (size_t)BT * Ee);
    float* pmax = rnll + BT;
    float* psum = pmax + (size_t)BT * NT2;
    const size_t need = OFF + (size_t)BT * Ee * 2
                      + (BT + 2 * (size_t)BT * NT2) * sizeof(float);
    if (ws_size < need) return;

    k_embed<<<BT, 256, 0, stream>>>(idx, wte, wpe, x);
    for (int l = 0; l < Ll; l++) {
        k_ln<<<BT, 256, 0, stream>>>(x, ln1_g + (size_t)l * Ee, ln1_b + (size_t)l * Ee, h);
        k_wT<<<dim3(3 * Ee / 32, Ee / 32), 256, 0, stream>>>(
            qkv_w + (size_t)l * Ee * 3 * Ee, wT, Ee, 3 * Ee);
        k_gemm<0, 1, 0, short><<<dim3(BT / 128, 3 * Ee / 128), 256, 0, stream>>>(
            h, wT, nullptr, nullptr, qkvb, BT, 3 * Ee, Ee, nullptr, nullptr, 0);
        k_attn<<<dim3(Tt / 64, Hh, Bb), 256, 0, stream>>>(qkvb, y);
        k_wT<<<dim3(Ee / 32, Ee / 32), 256, 0, stream>>>(
            proj_w + (size_t)l * Ee * Ee, wT, Ee, Ee);
        k_gemm<3, 1, 1, float><<<dim3(BT / 128, Ee / 64), 256, 0, stream>>>(
            y, wT, proj_b + (size_t)l * Ee, x, x, BT, Ee, Ee, nullptr, nullptr, 0);
        k_ln<<<BT, 256, 0, stream>>>(x, ln2_g + (size_t)l * Ee, ln2_b + (size_t)l * Ee, h);
        k_wT<<<dim3(FFf / 32, Ee / 32), 256, 0, stream>>>(
            fc1_w + (size_t)l * Ee * FFf, wT, Ee, FFf);
        k_gemm<2, 1, 0, short><<<dim3(BT / 128, FFf / 128), 256, 0, stream>>>(
            h, wT, fc1_b + (size_t)l * FFf, nullptr, h1, BT, FFf, Ee, nullptr, nullptr, 0);
        k_wT<<<dim3(Ee / 32, FFf / 32), 256, 0, stream>>>(
            fc2_w + (size_t)l * FFf * Ee, wT, FFf, Ee);
        k_gemm<3, 1, 1, float><<<dim3(BT / 128, Ee / 64), 256, 0, stream>>>(
            h1, wT, fc2_b + (size_t)l * Ee, x, x, BT, Ee, FFf, nullptr, nullptr, 0);
    }
    k_ln<<<BT, 256, 0, stream>>>(x, lnf_g, lnf_b, h);
    // x (and all other overlay buffers) now dead -> write wteb over them
    k_cvt<<<(Vv * Ee / 8 + 255) / 256, 256, 0, stream>>>(wte, wteb, Vv * Ee / 8);
    k_gemm<4, 1, 0, float><<<dim3(BT / 128, (Vv + 127) / 128), 256, 0, stream>>>(
        h, wteb, nullptr, nullptr, logits, BT, Vv, Ee, pmax, psum, NT2);
    k_loss_fin<<<BT / 4, 256, 0, stream>>>(pmax, psum, logits, targets, rnll, NT2);
    k_loss_final<<<1, 256, 0, stream>>>(rnll, loss);
}